// Round 1
// baseline (3717.422 us; speedup 1.0000x reference)
//
#include <hip/hip_runtime.h>
#include <math.h>

// Problem constants (match reference)
#define B_      4
#define L_      1024
#define D_INNC  8      // D_IN
#define DMODEL  512
#define DEPTH_  4
#define DINNER  1024
#define DSTATE  16
#define DCONV   4
#define DTRANK  32
#define MTOT    (B_*L_)   // 4096

// ---------------------------------------------------------------------------
// h = x @ in_w^T + in_b    (4096 x 512, K=8)
__global__ __launch_bounds__(256) void in_proj_kernel(
    const float* __restrict__ x, const float* __restrict__ w,
    const float* __restrict__ bias, float* __restrict__ h)
{
    int idx = blockIdx.x * 256 + threadIdx.x;      // over MTOT*DMODEL
    int m = idx / DMODEL, d = idx % DMODEL;
    const float* xr = x + m * D_INNC;
    const float* wr = w + d * D_INNC;
    float acc = bias[d];
#pragma unroll
    for (int k = 0; k < D_INNC; ++k) acc += xr[k] * wr[k];
    h[idx] = acc;
}

// ---------------------------------------------------------------------------
// Generic NT GEMM: C[m,n] = sum_k A[m,k] * B[n,k]
// BM=BN=64, BK=16, 256 threads, 4x4 per thread. M%64==0, N%64==0, K%16==0.
__global__ __launch_bounds__(256) void gemm_nt64(
    const float* __restrict__ A, int lda,
    const float* __restrict__ B, int ldb,
    float* __restrict__ C, int ldc, int K)
{
    __shared__ float As[16][64];
    __shared__ float Bs[16][64];

    const int tx = threadIdx.x % 16;   // n direction
    const int ty = threadIdx.x / 16;   // m direction
    const int m0 = blockIdx.y * 64;
    const int n0 = blockIdx.x * 64;

    const int tm = threadIdx.x / 4;    // 0..63 row within tile
    const int tk = threadIdx.x % 4;    // 0..3  k-group (x4 floats)

    const float* Aload = A + (size_t)(m0 + tm) * lda + tk * 4;
    const float* Bload = B + (size_t)(n0 + tm) * ldb + tk * 4;

    float acc[4][4] = {};

    for (int k0 = 0; k0 < K; k0 += 16) {
        float4 av = *(const float4*)(Aload + k0);
        float4 bv = *(const float4*)(Bload + k0);
        __syncthreads();
        As[tk*4+0][tm] = av.x; As[tk*4+1][tm] = av.y;
        As[tk*4+2][tm] = av.z; As[tk*4+3][tm] = av.w;
        Bs[tk*4+0][tm] = bv.x; Bs[tk*4+1][tm] = bv.y;
        Bs[tk*4+2][tm] = bv.z; Bs[tk*4+3][tm] = bv.w;
        __syncthreads();
#pragma unroll
        for (int k = 0; k < 16; ++k) {
            float4 a4 = *(const float4*)&As[k][ty*4];
            float4 b4 = *(const float4*)&Bs[k][tx*4];
            acc[0][0] += a4.x*b4.x; acc[0][1] += a4.x*b4.y; acc[0][2] += a4.x*b4.z; acc[0][3] += a4.x*b4.w;
            acc[1][0] += a4.y*b4.x; acc[1][1] += a4.y*b4.y; acc[1][2] += a4.y*b4.z; acc[1][3] += a4.y*b4.w;
            acc[2][0] += a4.z*b4.x; acc[2][1] += a4.z*b4.y; acc[2][2] += a4.z*b4.z; acc[2][3] += a4.z*b4.w;
            acc[3][0] += a4.w*b4.x; acc[3][1] += a4.w*b4.y; acc[3][2] += a4.w*b4.z; acc[3][3] += a4.w*b4.w;
        }
    }
#pragma unroll
    for (int i = 0; i < 4; ++i) {
        float4 o = make_float4(acc[i][0], acc[i][1], acc[i][2], acc[i][3]);
        *(float4*)&C[(size_t)(m0 + ty*4 + i) * ldc + n0 + tx*4] = o;
    }
}

// ---------------------------------------------------------------------------
// Depthwise causal conv (k=4) + bias + SiLU. Reads xc = xz[:, 0:1024].
__global__ __launch_bounds__(256) void conv_silu_kernel(
    const float* __restrict__ xz, const float* __restrict__ cw,
    const float* __restrict__ cb, float* __restrict__ u)
{
    int idx = blockIdx.x * 256 + threadIdx.x;   // MTOT*DINNER
    int m = idx >> 10;
    int d = idx & (DINNER - 1);
    int l = m & (L_ - 1);

    const float4 w = *(const float4*)&cw[d * 4];
    float acc = cb[d];
    // tap k multiplies xc[l + k - 3]
    if (l >= 3) acc += xz[(size_t)(m-3) * 2048 + d] * w.x;
    if (l >= 2) acc += xz[(size_t)(m-2) * 2048 + d] * w.y;
    if (l >= 1) acc += xz[(size_t)(m-1) * 2048 + d] * w.z;
    acc             += xz[(size_t)m     * 2048 + d] * w.w;
    u[idx] = acc / (1.f + __expf(-acc));   // silu
}

// ---------------------------------------------------------------------------
// dt = softplus(dt_lr @ Wdt^T + b_dt); dt_lr = xdbl[:, 0:32] (row stride 64)
__global__ __launch_bounds__(256) void dt_kernel(
    const float* __restrict__ xdbl, const float* __restrict__ Wdt,
    const float* __restrict__ bdt, float* __restrict__ dt)
{
    __shared__ float a[DTRANK];
    int m = blockIdx.x;
    if (threadIdx.x < DTRANK) a[threadIdx.x] = xdbl[(size_t)m * 64 + threadIdx.x];
    __syncthreads();
    for (int n = threadIdx.x; n < DINNER; n += 256) {
        const float* w = Wdt + (size_t)n * DTRANK;
        float acc = bdt[n];
#pragma unroll
        for (int k = 0; k < DTRANK; ++k) acc += a[k] * w[k];
        // softplus, numerically stable
        float sp = (acc > 20.f) ? acc : log1pf(expf(acc));
        dt[(size_t)m * DINNER + n] = sp;
    }
}

// ---------------------------------------------------------------------------
// Selective scan. One 16-lane group per (b,d); lane = state s.
// Fuses: y_scan + u*D, then * silu(z); writes y.
__global__ __launch_bounds__(256) void scan_kernel(
    const float* __restrict__ xz,    // z at [m*2048 + 1024 + d]
    const float* __restrict__ u,
    const float* __restrict__ xdbl,  // B at [m*64+32+s], C at [m*64+48+s]
    const float* __restrict__ dt,
    const float* __restrict__ A_log, // [d*16+s] (layer slice)
    const float* __restrict__ Dp,    // [d]
    float* __restrict__ y)
{
    const int s = threadIdx.x & 15;
    const int g = threadIdx.x >> 4;          // 16 groups / block
    const int b = blockIdx.x >> 6;           // 64 d-chunks per batch
    const int d = ((blockIdx.x & 63) << 4) + g;

    const float Aval = -__expf(A_log[d * DSTATE + s]);
    const float Dval = Dp[d];
    float hst = 0.f;
    const int mbase = b * L_;

    for (int l0 = 0; l0 < L_; l0 += 8) {
        float dt8[8], u8[8], B8[8], C8[8];
#pragma unroll
        for (int j = 0; j < 8; ++j) {
            int m = mbase + l0 + j;
            dt8[j] = dt[(size_t)m * DINNER + d];
            u8[j]  = u [(size_t)m * DINNER + d];
            B8[j]  = xdbl[(size_t)m * 64 + 32 + s];
            C8[j]  = xdbl[(size_t)m * 64 + 48 + s];
        }
#pragma unroll
        for (int j = 0; j < 8; ++j) {
            float dtv = dt8[j];
            float dA  = __expf(dtv * Aval);
            hst = dA * hst + dtv * B8[j] * u8[j];
            float part = hst * C8[j];
            part += __shfl_xor(part, 8);
            part += __shfl_xor(part, 4);
            part += __shfl_xor(part, 2);
            part += __shfl_xor(part, 1);
            if (s == 0) {
                int m = mbase + l0 + j;
                float zv = xz[(size_t)m * 2048 + 1024 + d];
                float sz = zv / (1.f + __expf(-zv));
                y[(size_t)m * DINNER + d] = (part + u8[j] * Dval) * sz;
            }
        }
    }
}

// ---------------------------------------------------------------------------
// Final LayerNorm over DMODEL=512. One block per row, 256 threads x 2 elems.
__global__ __launch_bounds__(256) void ln_kernel(
    const float* __restrict__ h, const float* __restrict__ g,
    const float* __restrict__ bta, float* __restrict__ out)
{
    int m = blockIdx.x;
    const float* row = h + (size_t)m * DMODEL;
    int t = threadIdx.x;
    float v0 = row[t], v1 = row[t + 256];
    float sum = v0 + v1, sq = v0*v0 + v1*v1;
#pragma unroll
    for (int off = 32; off; off >>= 1) {
        sum += __shfl_down(sum, off);
        sq  += __shfl_down(sq,  off);
    }
    __shared__ float ls[4], lq[4];
    int w = t >> 6;
    if ((t & 63) == 0) { ls[w] = sum; lq[w] = sq; }
    __syncthreads();
    sum = ls[0] + ls[1] + ls[2] + ls[3];
    sq  = lq[0] + lq[1] + lq[2] + lq[3];
    float mu  = sum * (1.f / DMODEL);
    float var = sq * (1.f / DMODEL) - mu * mu;
    float rs  = rsqrtf(var + 1e-5f);
    out[(size_t)m * DMODEL + t]       = (v0 - mu) * rs * g[t]       + bta[t];
    out[(size_t)m * DMODEL + t + 256] = (v1 - mu) * rs * g[t + 256] + bta[t + 256];
}

// ---------------------------------------------------------------------------
extern "C" void kernel_launch(void* const* d_in, const int* in_sizes, int n_in,
                              void* d_out, int out_size, void* d_ws, size_t ws_size,
                              hipStream_t stream)
{
    const float* x      = (const float*)d_in[0];
    const float* in_w   = (const float*)d_in[1];
    const float* in_b   = (const float*)d_in[2];
    const float* W_xz   = (const float*)d_in[3];
    const float* conv_w = (const float*)d_in[4];
    const float* conv_b = (const float*)d_in[5];
    const float* W_xp   = (const float*)d_in[6];
    const float* W_dt   = (const float*)d_in[7];
    const float* b_dt   = (const float*)d_in[8];
    const float* A_log  = (const float*)d_in[9];
    const float* D_par  = (const float*)d_in[10];
    const float* W_out  = (const float*)d_in[11];
    const float* ln_g   = (const float*)d_in[12];
    const float* ln_b   = (const float*)d_in[13];
    float* out = (float*)d_out;

    // Workspace layout (floats). Total = 4096*(512+2048+1024+64+1024+1024)
    //   = 23,330,816 floats = 93.3 MB.
    float* ws   = (float*)d_ws;
    float* h    = ws;                        // 4096*512
    float* xz   = h    + (size_t)MTOT*DMODEL;     // 4096*2048
    float* u    = xz   + (size_t)MTOT*2*DINNER;   // 4096*1024
    float* xdbl = u    + (size_t)MTOT*DINNER;     // 4096*64
    float* dt   = xdbl + (size_t)MTOT*64;         // 4096*1024
    float* y    = dt   + (size_t)MTOT*DINNER;     // 4096*1024

    in_proj_kernel<<<MTOT*DMODEL/256, 256, 0, stream>>>(x, in_w, in_b, h);

    for (int layer = 0; layer < DEPTH_; ++layer) {
        const float* Wxz  = W_xz   + (size_t)layer * 2048 * DMODEL;
        const float* cw   = conv_w + (size_t)layer * DINNER * DCONV;
        const float* cb   = conv_b + (size_t)layer * DINNER;
        const float* Wxp  = W_xp   + (size_t)layer * 64 * DINNER;
        const float* Wdt  = W_dt   + (size_t)layer * DINNER * DTRANK;
        const float* bdt  = b_dt   + (size_t)layer * DINNER;
        const float* Alog = A_log  + (size_t)layer * DINNER * DSTATE;
        const float* Dp   = D_par  + (size_t)layer * DINNER;
        const float* Wout = W_out  + (size_t)layer * DMODEL * DINNER;

        // xz = h @ Wxz^T : (4096 x 2048), K=512
        gemm_nt64<<<dim3(2048/64, MTOT/64), 256, 0, stream>>>(h, DMODEL, Wxz, DMODEL, xz, 2048, DMODEL);
        // u = silu(conv(xc) + cb)
        conv_silu_kernel<<<MTOT*DINNER/256, 256, 0, stream>>>(xz, cw, cb, u);
        // xdbl = u @ Wxp^T : (4096 x 64), K=1024
        gemm_nt64<<<dim3(1, MTOT/64), 256, 0, stream>>>(u, DINNER, Wxp, DINNER, xdbl, 64, DINNER);
        // dt = softplus(dt_lr @ Wdt^T + b_dt) : (4096 x 1024)
        dt_kernel<<<MTOT, 256, 0, stream>>>(xdbl, Wdt, bdt, dt);
        // selective scan -> y (fused +u*D, *silu(z))
        scan_kernel<<<B_ * (DINNER/16) / 16, 256, 0, stream>>>(xz, u, xdbl, dt, Alog, Dp, y);
        // h = y @ Wout^T : (4096 x 512), K=1024
        gemm_nt64<<<dim3(DMODEL/64, MTOT/64), 256, 0, stream>>>(y, DINNER, Wout, DINNER, h, DMODEL, DINNER);
    }

    ln_kernel<<<MTOT, 256, 0, stream>>>(h, ln_g, ln_b, out);
}

// Round 2
// 2256.170 us; speedup vs baseline: 1.6477x; 1.6477x over previous
//
#include <hip/hip_runtime.h>
#include <math.h>

// Problem constants (match reference)
#define B_      4
#define L_      1024
#define D_INNC  8      // D_IN
#define DMODEL  512
#define DEPTH_  4
#define DINNER  1024
#define DSTATE  16
#define DCONV   4
#define DTRANK  32
#define MTOT    (B_*L_)   // 4096

// ---------------------------------------------------------------------------
// h = x @ in_w^T + in_b    (4096 x 512, K=8)
__global__ __launch_bounds__(256) void in_proj_kernel(
    const float* __restrict__ x, const float* __restrict__ w,
    const float* __restrict__ bias, float* __restrict__ h)
{
    int idx = blockIdx.x * 256 + threadIdx.x;      // over MTOT*DMODEL
    int m = idx / DMODEL, d = idx % DMODEL;
    const float* xr = x + m * D_INNC;
    const float* wr = w + d * D_INNC;
    float acc = bias[d];
#pragma unroll
    for (int k = 0; k < D_INNC; ++k) acc += xr[k] * wr[k];
    h[idx] = acc;
}

// ---------------------------------------------------------------------------
// Generic NT GEMM (small-N path): C[m,n] = sum_k A[m,k] * B[n,k]
// BM=BN=64, BK=16, 256 threads, 4x4 per thread.
__global__ __launch_bounds__(256) void gemm_nt64(
    const float* __restrict__ A, int lda,
    const float* __restrict__ B, int ldb,
    float* __restrict__ C, int ldc, int K)
{
    __shared__ float As[16][64];
    __shared__ float Bs[16][64];

    const int tx = threadIdx.x % 16;   // n direction
    const int ty = threadIdx.x / 16;   // m direction
    const int m0 = blockIdx.y * 64;
    const int n0 = blockIdx.x * 64;

    const int tm = threadIdx.x / 4;    // 0..63 row within tile
    const int tk = threadIdx.x % 4;    // 0..3  k-group (x4 floats)

    const float* Aload = A + (size_t)(m0 + tm) * lda + tk * 4;
    const float* Bload = B + (size_t)(n0 + tm) * ldb + tk * 4;

    float acc[4][4] = {};

    for (int k0 = 0; k0 < K; k0 += 16) {
        float4 av = *(const float4*)(Aload + k0);
        float4 bv = *(const float4*)(Bload + k0);
        __syncthreads();
        As[tk*4+0][tm] = av.x; As[tk*4+1][tm] = av.y;
        As[tk*4+2][tm] = av.z; As[tk*4+3][tm] = av.w;
        Bs[tk*4+0][tm] = bv.x; Bs[tk*4+1][tm] = bv.y;
        Bs[tk*4+2][tm] = bv.z; Bs[tk*4+3][tm] = bv.w;
        __syncthreads();
#pragma unroll
        for (int k = 0; k < 16; ++k) {
            float4 a4 = *(const float4*)&As[k][ty*4];
            float4 b4 = *(const float4*)&Bs[k][tx*4];
            acc[0][0] += a4.x*b4.x; acc[0][1] += a4.x*b4.y; acc[0][2] += a4.x*b4.z; acc[0][3] += a4.x*b4.w;
            acc[1][0] += a4.y*b4.x; acc[1][1] += a4.y*b4.y; acc[1][2] += a4.y*b4.z; acc[1][3] += a4.y*b4.w;
            acc[2][0] += a4.z*b4.x; acc[2][1] += a4.z*b4.y; acc[2][2] += a4.z*b4.z; acc[2][3] += a4.z*b4.w;
            acc[3][0] += a4.w*b4.x; acc[3][1] += a4.w*b4.y; acc[3][2] += a4.w*b4.z; acc[3][3] += a4.w*b4.w;
        }
    }
#pragma unroll
    for (int i = 0; i < 4; ++i) {
        float4 o = make_float4(acc[i][0], acc[i][1], acc[i][2], acc[i][3]);
        *(float4*)&C[(size_t)(m0 + ty*4 + i) * ldc + n0 + tx*4] = o;
    }
}

// ---------------------------------------------------------------------------
// Big-tile NT GEMM: BM=BN=128, BK=16, 256 threads, 8x8 per thread.
// C[m,n] = sum_k A[m,k]*B[n,k]. M%128==0, N%128==0, K%16==0.
__global__ __launch_bounds__(256) void gemm_nt128(
    const float* __restrict__ A, int lda,
    const float* __restrict__ B, int ldb,
    float* __restrict__ C, int ldc, int K)
{
    __shared__ float As[16][128];
    __shared__ float Bs[16][128];

    const int tx = threadIdx.x & 15;     // n micro index
    const int ty = threadIdx.x >> 4;     // m micro index
    const int m0 = blockIdx.y * 128;
    const int n0 = blockIdx.x * 128;

    const int lrow = threadIdx.x >> 1;        // 0..127 tile row
    const int lk   = (threadIdx.x & 1) * 8;   // 0 or 8

    const float* Aload = A + (size_t)(m0 + lrow) * lda + lk;
    const float* Bload = B + (size_t)(n0 + lrow) * ldb + lk;

    float acc[8][8] = {};

    for (int k0 = 0; k0 < K; k0 += 16) {
        float4 a0 = *(const float4*)(Aload + k0);
        float4 a1 = *(const float4*)(Aload + k0 + 4);
        float4 b0 = *(const float4*)(Bload + k0);
        float4 b1 = *(const float4*)(Bload + k0 + 4);
        __syncthreads();
        float av[8] = {a0.x,a0.y,a0.z,a0.w,a1.x,a1.y,a1.z,a1.w};
        float bv[8] = {b0.x,b0.y,b0.z,b0.w,b1.x,b1.y,b1.z,b1.w};
#pragma unroll
        for (int q = 0; q < 8; ++q) { As[lk+q][lrow] = av[q]; Bs[lk+q][lrow] = bv[q]; }
        __syncthreads();
#pragma unroll
        for (int k = 0; k < 16; ++k) {
            float am[8], bn[8];
            *(float4*)&am[0] = *(const float4*)&As[k][ty*8];
            *(float4*)&am[4] = *(const float4*)&As[k][ty*8+4];
            *(float4*)&bn[0] = *(const float4*)&Bs[k][tx*8];
            *(float4*)&bn[4] = *(const float4*)&Bs[k][tx*8+4];
#pragma unroll
            for (int i = 0; i < 8; ++i)
#pragma unroll
                for (int j = 0; j < 8; ++j)
                    acc[i][j] += am[i] * bn[j];
        }
    }
#pragma unroll
    for (int i = 0; i < 8; ++i) {
        size_t row = (size_t)(m0 + ty*8 + i);
        *(float4*)&C[row*ldc + n0 + tx*8]     = make_float4(acc[i][0],acc[i][1],acc[i][2],acc[i][3]);
        *(float4*)&C[row*ldc + n0 + tx*8 + 4] = make_float4(acc[i][4],acc[i][5],acc[i][6],acc[i][7]);
    }
}

// ---------------------------------------------------------------------------
// Depthwise causal conv (k=4) + bias + SiLU. Reads xc = xz[:, 0:1024].
__global__ __launch_bounds__(256) void conv_silu_kernel(
    const float* __restrict__ xz, const float* __restrict__ cw,
    const float* __restrict__ cb, float* __restrict__ u)
{
    int idx = blockIdx.x * 256 + threadIdx.x;   // MTOT*DINNER
    int m = idx >> 10;
    int d = idx & (DINNER - 1);
    int l = m & (L_ - 1);

    const float4 w = *(const float4*)&cw[d * 4];
    float acc = cb[d];
    if (l >= 3) acc += xz[(size_t)(m-3) * 2048 + d] * w.x;
    if (l >= 2) acc += xz[(size_t)(m-2) * 2048 + d] * w.y;
    if (l >= 1) acc += xz[(size_t)(m-1) * 2048 + d] * w.z;
    acc             += xz[(size_t)m     * 2048 + d] * w.w;
    u[idx] = acc / (1.f + __expf(-acc));   // silu
}

// ---------------------------------------------------------------------------
// dt = softplus(dt_lr @ Wdt^T + b_dt); 8 rows of m per block (reuse Wdt).
__global__ __launch_bounds__(256) void dt_kernel(
    const float* __restrict__ xdbl, const float* __restrict__ Wdt,
    const float* __restrict__ bdt, float* __restrict__ dt)
{
    __shared__ float a[8][DTRANK];
    const int m0 = blockIdx.x * 8;
    const int t = threadIdx.x;
    if (t < 8 * DTRANK) a[t >> 5][t & 31] = xdbl[(size_t)(m0 + (t >> 5)) * 64 + (t & 31)];
    __syncthreads();
    for (int n = t; n < DINNER; n += 256) {
        const float* w = Wdt + (size_t)n * DTRANK;
        float bb = bdt[n];
        float acc[8];
#pragma unroll
        for (int r = 0; r < 8; ++r) acc[r] = bb;
#pragma unroll
        for (int k = 0; k < DTRANK; ++k) {
            float wk = w[k];
#pragma unroll
            for (int r = 0; r < 8; ++r) acc[r] += a[r][k] * wk;
        }
#pragma unroll
        for (int r = 0; r < 8; ++r) {
            float v = acc[r];
            float sp = (v > 20.f) ? v : log1pf(expf(v));
            dt[(size_t)(m0 + r) * DINNER + n] = sp;
        }
    }
}

// ---------------------------------------------------------------------------
// Selective scan. One 16-lane group per (b,d); lane = state s.
// Grid: (B_*DINNER)/16 = 256 blocks of 256 threads (16 groups each).
// Fuses: y_scan + u*D, then * silu(z); writes y.
__global__ __launch_bounds__(256) void scan_kernel(
    const float* __restrict__ xz,    // z at [m*2048 + 1024 + d]
    const float* __restrict__ u,
    const float* __restrict__ xdbl,  // B at [m*64+32+s], C at [m*64+48+s]
    const float* __restrict__ dt,
    const float* __restrict__ A_log, // [d*16+s] (layer slice)
    const float* __restrict__ Dp,    // [d]
    float* __restrict__ y)
{
    const int s   = threadIdx.x & 15;
    const int g   = threadIdx.x >> 4;            // 16 groups / block
    const int gid = blockIdx.x * 16 + g;         // 0..4095 over (b,d)
    const int b   = gid >> 10;
    const int d   = gid & (DINNER - 1);

    const float Aval = -__expf(A_log[d * DSTATE + s]);
    const float Dval = Dp[d];
    float hst = 0.f;
    const int mbase = b * L_;

    for (int l0 = 0; l0 < L_; l0 += 8) {
        float dt8[8], u8[8], B8[8], C8[8], z8[8];
#pragma unroll
        for (int j = 0; j < 8; ++j) {
            int m = mbase + l0 + j;
            dt8[j] = dt[(size_t)m * DINNER + d];
            u8[j]  = u [(size_t)m * DINNER + d];
            B8[j]  = xdbl[(size_t)m * 64 + 32 + s];
            C8[j]  = xdbl[(size_t)m * 64 + 48 + s];
            z8[j]  = xz[(size_t)m * 2048 + DINNER + d];
        }
        float part8[8];
#pragma unroll
        for (int j = 0; j < 8; ++j) {
            float dtv = dt8[j];
            float dA  = __expf(dtv * Aval);
            hst = dA * hst + dtv * B8[j] * u8[j];
            part8[j] = hst * C8[j];
        }
        // 8 independent butterfly chains -> ds latency overlapped
#pragma unroll
        for (int off = 8; off; off >>= 1) {
#pragma unroll
            for (int j = 0; j < 8; ++j)
                part8[j] += __shfl_xor(part8[j], off);
        }
        if (s == 0) {
#pragma unroll
            for (int j = 0; j < 8; ++j) {
                int m = mbase + l0 + j;
                float zv = z8[j];
                float sz = zv / (1.f + __expf(-zv));
                y[(size_t)m * DINNER + d] = (part8[j] + u8[j] * Dval) * sz;
            }
        }
    }
}

// ---------------------------------------------------------------------------
// Final LayerNorm over DMODEL=512. One block per row, 256 threads x 2 elems.
__global__ __launch_bounds__(256) void ln_kernel(
    const float* __restrict__ h, const float* __restrict__ g,
    const float* __restrict__ bta, float* __restrict__ out)
{
    int m = blockIdx.x;
    const float* row = h + (size_t)m * DMODEL;
    int t = threadIdx.x;
    float v0 = row[t], v1 = row[t + 256];
    float sum = v0 + v1, sq = v0*v0 + v1*v1;
#pragma unroll
    for (int off = 32; off; off >>= 1) {
        sum += __shfl_down(sum, off);
        sq  += __shfl_down(sq,  off);
    }
    __shared__ float ls[4], lq[4];
    int w = t >> 6;
    if ((t & 63) == 0) { ls[w] = sum; lq[w] = sq; }
    __syncthreads();
    sum = ls[0] + ls[1] + ls[2] + ls[3];
    sq  = lq[0] + lq[1] + lq[2] + lq[3];
    float mu  = sum * (1.f / DMODEL);
    float var = sq * (1.f / DMODEL) - mu * mu;
    float rs  = rsqrtf(var + 1e-5f);
    out[(size_t)m * DMODEL + t]       = (v0 - mu) * rs * g[t]       + bta[t];
    out[(size_t)m * DMODEL + t + 256] = (v1 - mu) * rs * g[t + 256] + bta[t + 256];
}

// ---------------------------------------------------------------------------
extern "C" void kernel_launch(void* const* d_in, const int* in_sizes, int n_in,
                              void* d_out, int out_size, void* d_ws, size_t ws_size,
                              hipStream_t stream)
{
    const float* x      = (const float*)d_in[0];
    const float* in_w   = (const float*)d_in[1];
    const float* in_b   = (const float*)d_in[2];
    const float* W_xz   = (const float*)d_in[3];
    const float* conv_w = (const float*)d_in[4];
    const float* conv_b = (const float*)d_in[5];
    const float* W_xp   = (const float*)d_in[6];
    const float* W_dt   = (const float*)d_in[7];
    const float* b_dt   = (const float*)d_in[8];
    const float* A_log  = (const float*)d_in[9];
    const float* D_par  = (const float*)d_in[10];
    const float* W_out  = (const float*)d_in[11];
    const float* ln_g   = (const float*)d_in[12];
    const float* ln_b   = (const float*)d_in[13];
    float* out = (float*)d_out;

    // Workspace layout (floats). Total = 4096*(512+2048+1024+64+1024+1024)
    //   = 23,330,816 floats = 93.3 MB.
    float* ws   = (float*)d_ws;
    float* h    = ws;                             // 4096*512
    float* xz   = h    + (size_t)MTOT*DMODEL;     // 4096*2048
    float* u    = xz   + (size_t)MTOT*2*DINNER;   // 4096*1024
    float* xdbl = u    + (size_t)MTOT*DINNER;     // 4096*64
    float* dt   = xdbl + (size_t)MTOT*64;         // 4096*1024
    float* y    = dt   + (size_t)MTOT*DINNER;     // 4096*1024

    in_proj_kernel<<<MTOT*DMODEL/256, 256, 0, stream>>>(x, in_w, in_b, h);

    for (int layer = 0; layer < DEPTH_; ++layer) {
        const float* Wxz  = W_xz   + (size_t)layer * 2048 * DMODEL;
        const float* cw   = conv_w + (size_t)layer * DINNER * DCONV;
        const float* cb   = conv_b + (size_t)layer * DINNER;
        const float* Wxp  = W_xp   + (size_t)layer * 64 * DINNER;
        const float* Wdt  = W_dt   + (size_t)layer * DINNER * DTRANK;
        const float* bdt  = b_dt   + (size_t)layer * DINNER;
        const float* Alog = A_log  + (size_t)layer * DINNER * DSTATE;
        const float* Dp   = D_par  + (size_t)layer * DINNER;
        const float* Wout = W_out  + (size_t)layer * DMODEL * DINNER;

        // xz = h @ Wxz^T : (4096 x 2048), K=512
        gemm_nt128<<<dim3(2048/128, MTOT/128), 256, 0, stream>>>(h, DMODEL, Wxz, DMODEL, xz, 2048, DMODEL);
        // u = silu(conv(xc) + cb)
        conv_silu_kernel<<<MTOT*DINNER/256, 256, 0, stream>>>(xz, cw, cb, u);
        // xdbl = u @ Wxp^T : (4096 x 64), K=1024
        gemm_nt64<<<dim3(1, MTOT/64), 256, 0, stream>>>(u, DINNER, Wxp, DINNER, xdbl, 64, DINNER);
        // dt = softplus(dt_lr @ Wdt^T + b_dt) : (4096 x 1024)
        dt_kernel<<<MTOT/8, 256, 0, stream>>>(xdbl, Wdt, bdt, dt);
        // selective scan -> y (fused +u*D, *silu(z)); 4096 groups / 16 per block
        scan_kernel<<<(B_*DINNER)/16, 256, 0, stream>>>(xz, u, xdbl, dt, Alog, Dp, y);
        // h = y @ Wout^T : (4096 x 512), K=1024
        gemm_nt128<<<dim3(DMODEL/128, MTOT/128), 256, 0, stream>>>(y, DINNER, Wout, DINNER, h, DMODEL, DINNER);
    }

    ln_kernel<<<MTOT, 256, 0, stream>>>(h, ln_g, ln_b, out);
}

// Round 3
// 1477.425 us; speedup vs baseline: 2.5161x; 1.5271x over previous
//
#include <hip/hip_runtime.h>
#include <math.h>

// Problem constants (match reference)
#define B_      4
#define L_      1024
#define D_INNC  8      // D_IN
#define DMODEL  512
#define DEPTH_  4
#define DINNER  1024
#define DSTATE  16
#define DCONV   4
#define DTRANK  32
#define MTOT    (B_*L_)   // 4096
#define CHUNKS  16
#define CLEN    64        // L_/CHUNKS

// ---------------------------------------------------------------------------
// h = x @ in_w^T + in_b    (4096 x 512, K=8)
__global__ __launch_bounds__(256) void in_proj_kernel(
    const float* __restrict__ x, const float* __restrict__ w,
    const float* __restrict__ bias, float* __restrict__ h)
{
    int idx = blockIdx.x * 256 + threadIdx.x;      // over MTOT*DMODEL
    int m = idx / DMODEL, d = idx % DMODEL;
    const float* xr = x + m * D_INNC;
    const float* wr = w + d * D_INNC;
    float acc = bias[d];
#pragma unroll
    for (int k = 0; k < D_INNC; ++k) acc += xr[k] * wr[k];
    h[idx] = acc;
}

// ---------------------------------------------------------------------------
// NT GEMM 64x64 tile, 4x4/thread: C[m,n] = sum_k A[m,k]*B[n,k]
__global__ __launch_bounds__(256) void gemm_nt64(
    const float* __restrict__ A, int lda,
    const float* __restrict__ B, int ldb,
    float* __restrict__ C, int ldc, int K)
{
    __shared__ float As[16][64];
    __shared__ float Bs[16][64];

    const int tx = threadIdx.x % 16;
    const int ty = threadIdx.x / 16;
    const int m0 = blockIdx.y * 64;
    const int n0 = blockIdx.x * 64;

    const int tm = threadIdx.x / 4;
    const int tk = threadIdx.x % 4;

    const float* Aload = A + (size_t)(m0 + tm) * lda + tk * 4;
    const float* Bload = B + (size_t)(n0 + tm) * ldb + tk * 4;

    float acc[4][4] = {};

    for (int k0 = 0; k0 < K; k0 += 16) {
        float4 av = *(const float4*)(Aload + k0);
        float4 bv = *(const float4*)(Bload + k0);
        __syncthreads();
        As[tk*4+0][tm] = av.x; As[tk*4+1][tm] = av.y;
        As[tk*4+2][tm] = av.z; As[tk*4+3][tm] = av.w;
        Bs[tk*4+0][tm] = bv.x; Bs[tk*4+1][tm] = bv.y;
        Bs[tk*4+2][tm] = bv.z; Bs[tk*4+3][tm] = bv.w;
        __syncthreads();
#pragma unroll
        for (int k = 0; k < 16; ++k) {
            float4 a4 = *(const float4*)&As[k][ty*4];
            float4 b4 = *(const float4*)&Bs[k][tx*4];
            acc[0][0] += a4.x*b4.x; acc[0][1] += a4.x*b4.y; acc[0][2] += a4.x*b4.z; acc[0][3] += a4.x*b4.w;
            acc[1][0] += a4.y*b4.x; acc[1][1] += a4.y*b4.y; acc[1][2] += a4.y*b4.z; acc[1][3] += a4.y*b4.w;
            acc[2][0] += a4.z*b4.x; acc[2][1] += a4.z*b4.y; acc[2][2] += a4.z*b4.z; acc[2][3] += a4.z*b4.w;
            acc[3][0] += a4.w*b4.x; acc[3][1] += a4.w*b4.y; acc[3][2] += a4.w*b4.z; acc[3][3] += a4.w*b4.w;
        }
    }
#pragma unroll
    for (int i = 0; i < 4; ++i) {
        float4 o = make_float4(acc[i][0], acc[i][1], acc[i][2], acc[i][3]);
        *(float4*)&C[(size_t)(m0 + ty*4 + i) * ldc + n0 + tx*4] = o;
    }
}

// ---------------------------------------------------------------------------
// NT GEMM 128x128 tile, 8x8/thread (used for the wide xz GEMM).
__global__ __launch_bounds__(256) void gemm_nt128(
    const float* __restrict__ A, int lda,
    const float* __restrict__ B, int ldb,
    float* __restrict__ C, int ldc, int K)
{
    __shared__ float As[16][128];
    __shared__ float Bs[16][128];

    const int tx = threadIdx.x & 15;
    const int ty = threadIdx.x >> 4;
    const int m0 = blockIdx.y * 128;
    const int n0 = blockIdx.x * 128;

    const int lrow = threadIdx.x >> 1;
    const int lk   = (threadIdx.x & 1) * 8;

    const float* Aload = A + (size_t)(m0 + lrow) * lda + lk;
    const float* Bload = B + (size_t)(n0 + lrow) * ldb + lk;

    float acc[8][8] = {};

    for (int k0 = 0; k0 < K; k0 += 16) {
        float4 a0 = *(const float4*)(Aload + k0);
        float4 a1 = *(const float4*)(Aload + k0 + 4);
        float4 b0 = *(const float4*)(Bload + k0);
        float4 b1 = *(const float4*)(Bload + k0 + 4);
        __syncthreads();
        float av[8] = {a0.x,a0.y,a0.z,a0.w,a1.x,a1.y,a1.z,a1.w};
        float bv[8] = {b0.x,b0.y,b0.z,b0.w,b1.x,b1.y,b1.z,b1.w};
#pragma unroll
        for (int q = 0; q < 8; ++q) { As[lk+q][lrow] = av[q]; Bs[lk+q][lrow] = bv[q]; }
        __syncthreads();
#pragma unroll
        for (int k = 0; k < 16; ++k) {
            float am[8], bn[8];
            *(float4*)&am[0] = *(const float4*)&As[k][ty*8];
            *(float4*)&am[4] = *(const float4*)&As[k][ty*8+4];
            *(float4*)&bn[0] = *(const float4*)&Bs[k][tx*8];
            *(float4*)&bn[4] = *(const float4*)&Bs[k][tx*8+4];
#pragma unroll
            for (int i = 0; i < 8; ++i)
#pragma unroll
                for (int j = 0; j < 8; ++j)
                    acc[i][j] += am[i] * bn[j];
        }
    }
#pragma unroll
    for (int i = 0; i < 8; ++i) {
        size_t row = (size_t)(m0 + ty*8 + i);
        *(float4*)&C[row*ldc + n0 + tx*8]     = make_float4(acc[i][0],acc[i][1],acc[i][2],acc[i][3]);
        *(float4*)&C[row*ldc + n0 + tx*8 + 4] = make_float4(acc[i][4],acc[i][5],acc[i][6],acc[i][7]);
    }
}

// ---------------------------------------------------------------------------
// Depthwise causal conv (k=4) + bias + SiLU. Reads xc = xz[:, 0:1024].
__global__ __launch_bounds__(256) void conv_silu_kernel(
    const float* __restrict__ xz, const float* __restrict__ cw,
    const float* __restrict__ cb, float* __restrict__ u)
{
    int idx = blockIdx.x * 256 + threadIdx.x;   // MTOT*DINNER
    int m = idx >> 10;
    int d = idx & (DINNER - 1);
    int l = m & (L_ - 1);

    const float4 w = *(const float4*)&cw[d * 4];
    float acc = cb[d];
    if (l >= 3) acc += xz[(size_t)(m-3) * 2048 + d] * w.x;
    if (l >= 2) acc += xz[(size_t)(m-2) * 2048 + d] * w.y;
    if (l >= 1) acc += xz[(size_t)(m-1) * 2048 + d] * w.z;
    acc             += xz[(size_t)m     * 2048 + d] * w.w;
    u[idx] = acc / (1.f + __expf(-acc));   // silu
}

// ---------------------------------------------------------------------------
// x-proj partial GEMM: part[p][m][n] = sum_{k in split p} u[m,k]*W[n,k]
// BM=16, N=64, K-split 4x256. grid (4, 256).
__global__ __launch_bounds__(256) void xp_kernel(
    const float* __restrict__ u, const float* __restrict__ W,
    float* __restrict__ part)
{
    __shared__ float As[16][68];
    __shared__ float Ws[64][65];
    const int p  = blockIdx.x;
    const int m0 = blockIdx.y * 16;
    const int t  = threadIdx.x;
    const int kb = p * 256;
    const int n  = t & 63;
    const int mi = t >> 6;
    float acc[4] = {0.f, 0.f, 0.f, 0.f};

    for (int kt = 0; kt < 256; kt += 64) {
        const int k0 = kb + kt;
        __syncthreads();
        {   // stage A tile 16x64
            int r = t >> 4, cc = t & 15;
            float4 v = *(const float4*)&u[(size_t)(m0 + r) * DINNER + k0 + cc*4];
            As[r][cc*4+0] = v.x; As[r][cc*4+1] = v.y; As[r][cc*4+2] = v.z; As[r][cc*4+3] = v.w;
        }
        {   // stage W tile 64x64
            int r = t >> 2, f = t & 3;
#pragma unroll
            for (int q = 0; q < 4; ++q) {
                float4 v = *(const float4*)&W[(size_t)r * DINNER + k0 + f*16 + q*4];
                Ws[r][f*16+q*4+0] = v.x; Ws[r][f*16+q*4+1] = v.y;
                Ws[r][f*16+q*4+2] = v.z; Ws[r][f*16+q*4+3] = v.w;
            }
        }
        __syncthreads();
#pragma unroll 8
        for (int kk = 0; kk < 64; ++kk) {
            float w = Ws[n][kk];
#pragma unroll
            for (int j = 0; j < 4; ++j) acc[j] += As[mi*4+j][kk] * w;
        }
    }
#pragma unroll
    for (int j = 0; j < 4; ++j)
        part[((size_t)p * MTOT + m0 + mi*4 + j) * 64 + n] = acc[j];
}

// Sum the 4 K-split partials -> xdbl. float4 over MTOT*64 floats.
__global__ __launch_bounds__(256) void xpsum_kernel(
    const float* __restrict__ part, float* __restrict__ xdbl)
{
    int i = blockIdx.x * 256 + threadIdx.x;          // MTOT*64/4 = 65536
    const size_t stride = (size_t)MTOT * 64 / 4;
    const float4* p = (const float4*)part;
    float4 a = p[i], b = p[i + stride], c = p[i + 2*stride], d = p[i + 3*stride];
    float4 o = make_float4(a.x+b.x+c.x+d.x, a.y+b.y+c.y+d.y,
                           a.z+b.z+c.z+d.z, a.w+b.w+c.w+d.w);
    ((float4*)xdbl)[i] = o;
}

// ---------------------------------------------------------------------------
// dt = softplus(dt_lr @ Wdt^T + b_dt); 8 rows of m per block (reuse Wdt).
__global__ __launch_bounds__(256) void dt_kernel(
    const float* __restrict__ xdbl, const float* __restrict__ Wdt,
    const float* __restrict__ bdt, float* __restrict__ dt)
{
    __shared__ float a[8][DTRANK];
    const int m0 = blockIdx.x * 8;
    const int t = threadIdx.x;
    if (t < 8 * DTRANK) a[t >> 5][t & 31] = xdbl[(size_t)(m0 + (t >> 5)) * 64 + (t & 31)];
    __syncthreads();
    for (int n = t; n < DINNER; n += 256) {
        const float* w = Wdt + (size_t)n * DTRANK;
        float bb = bdt[n];
        float acc[8];
#pragma unroll
        for (int r = 0; r < 8; ++r) acc[r] = bb;
#pragma unroll
        for (int k = 0; k < DTRANK; ++k) {
            float wk = w[k];
#pragma unroll
            for (int r = 0; r < 8; ++r) acc[r] += a[r][k] * wk;
        }
#pragma unroll
        for (int r = 0; r < 8; ++r) {
            float v = acc[r];
            float sp = (v > 20.f) ? v : log1pf(expf(v));
            dt[(size_t)(m0 + r) * DINNER + n] = sp;
        }
    }
}

// ---------------------------------------------------------------------------
// Chunked selective scan, pass 1: per (b,d,chunk) local scan from h=0.
// Writes final local state hfinal and cumprod(dA) per state.
// gid = b*16384 + c*1024 + d  (d fastest for coalescing). 4096 blocks.
__global__ __launch_bounds__(256) void scan1_kernel(
    const float* __restrict__ u, const float* __restrict__ xdbl,
    const float* __restrict__ dt, const float* __restrict__ A_log,
    float* __restrict__ hfinal, float* __restrict__ cumA)
{
    const int s   = threadIdx.x & 15;
    const int g   = threadIdx.x >> 4;
    const int gid = blockIdx.x * 16 + g;
    const int d   = gid & (DINNER - 1);
    const int c   = (gid >> 10) & (CHUNKS - 1);
    const int b   = gid >> 14;

    const float Aval = -__expf(A_log[d * DSTATE + s]);
    float h = 0.f, cum = 1.f;
    const int mbase = b * L_ + c * CLEN;

    for (int t0 = 0; t0 < CLEN; t0 += 8) {
        float dt8[8], u8[8], B8[8];
#pragma unroll
        for (int j = 0; j < 8; ++j) {
            int m = mbase + t0 + j;
            dt8[j] = dt[(size_t)m * DINNER + d];
            u8[j]  = u [(size_t)m * DINNER + d];
            B8[j]  = xdbl[(size_t)m * 64 + 32 + s];
        }
#pragma unroll
        for (int j = 0; j < 8; ++j) {
            float dA = __expf(dt8[j] * Aval);
            cum *= dA;
            h = dA * h + dt8[j] * B8[j] * u8[j];
        }
    }
    size_t idx = ((size_t)(b * CHUNKS + c) * DINNER + d) * DSTATE + s;
    hfinal[idx] = h;
    cumA[idx]   = cum;
}

// Pass 2: sequential chunk fix-up, in place: hfinal[c] <- h_start(c).
__global__ __launch_bounds__(256) void scan2_kernel(
    float* __restrict__ hfinal, const float* __restrict__ cumA)
{
    int t = blockIdx.x * 256 + threadIdx.x;   // 65536 = B_*DINNER*DSTATE
    int s = t & 15, d = (t >> 4) & (DINNER - 1), b = t >> 14;
    float h = 0.f;
    for (int c = 0; c < CHUNKS; ++c) {
        size_t idx = ((size_t)(b * CHUNKS + c) * DINNER + d) * DSTATE + s;
        float hf = hfinal[idx], cA = cumA[idx];
        hfinal[idx] = h;          // becomes h_start for chunk c
        h = cA * h + hf;
    }
}

// Pass 3: re-run local scan seeded with true h_start; fuse y = (C.h + u*D)*silu(z).
__global__ __launch_bounds__(256) void scan3_kernel(
    const float* __restrict__ xz, const float* __restrict__ u,
    const float* __restrict__ xdbl, const float* __restrict__ dt,
    const float* __restrict__ A_log, const float* __restrict__ Dp,
    const float* __restrict__ hstart, float* __restrict__ y)
{
    const int s   = threadIdx.x & 15;
    const int g   = threadIdx.x >> 4;
    const int gid = blockIdx.x * 16 + g;
    const int d   = gid & (DINNER - 1);
    const int c   = (gid >> 10) & (CHUNKS - 1);
    const int b   = gid >> 14;

    const float Aval = -__expf(A_log[d * DSTATE + s]);
    const float Dval = Dp[d];
    size_t sidx = ((size_t)(b * CHUNKS + c) * DINNER + d) * DSTATE + s;
    float hst = hstart[sidx];
    const int mbase = b * L_ + c * CLEN;

    for (int t0 = 0; t0 < CLEN; t0 += 8) {
        float dt8[8], u8[8], B8[8], C8[8], z8[8];
#pragma unroll
        for (int j = 0; j < 8; ++j) {
            int m = mbase + t0 + j;
            dt8[j] = dt[(size_t)m * DINNER + d];
            u8[j]  = u [(size_t)m * DINNER + d];
            B8[j]  = xdbl[(size_t)m * 64 + 32 + s];
            C8[j]  = xdbl[(size_t)m * 64 + 48 + s];
            z8[j]  = xz[(size_t)m * 2048 + DINNER + d];
        }
        float part8[8];
#pragma unroll
        for (int j = 0; j < 8; ++j) {
            float dtv = dt8[j];
            float dA  = __expf(dtv * Aval);
            hst = dA * hst + dtv * B8[j] * u8[j];
            part8[j] = hst * C8[j];
        }
#pragma unroll
        for (int off = 8; off; off >>= 1) {
#pragma unroll
            for (int j = 0; j < 8; ++j)
                part8[j] += __shfl_xor(part8[j], off);
        }
        if (s == 0) {
#pragma unroll
            for (int j = 0; j < 8; ++j) {
                int m = mbase + t0 + j;
                float zv = z8[j];
                float sz = zv / (1.f + __expf(-zv));
                y[(size_t)m * DINNER + d] = (part8[j] + u8[j] * Dval) * sz;
            }
        }
    }
}

// ---------------------------------------------------------------------------
// Final LayerNorm over DMODEL=512.
__global__ __launch_bounds__(256) void ln_kernel(
    const float* __restrict__ h, const float* __restrict__ g,
    const float* __restrict__ bta, float* __restrict__ out)
{
    int m = blockIdx.x;
    const float* row = h + (size_t)m * DMODEL;
    int t = threadIdx.x;
    float v0 = row[t], v1 = row[t + 256];
    float sum = v0 + v1, sq = v0*v0 + v1*v1;
#pragma unroll
    for (int off = 32; off; off >>= 1) {
        sum += __shfl_down(sum, off);
        sq  += __shfl_down(sq,  off);
    }
    __shared__ float ls[4], lq[4];
    int w = t >> 6;
    if ((t & 63) == 0) { ls[w] = sum; lq[w] = sq; }
    __syncthreads();
    sum = ls[0] + ls[1] + ls[2] + ls[3];
    sq  = lq[0] + lq[1] + lq[2] + lq[3];
    float mu  = sum * (1.f / DMODEL);
    float var = sq * (1.f / DMODEL) - mu * mu;
    float rs  = rsqrtf(var + 1e-5f);
    out[(size_t)m * DMODEL + t]       = (v0 - mu) * rs * g[t]       + bta[t];
    out[(size_t)m * DMODEL + t + 256] = (v1 - mu) * rs * g[t + 256] + bta[t + 256];
}

// ---------------------------------------------------------------------------
extern "C" void kernel_launch(void* const* d_in, const int* in_sizes, int n_in,
                              void* d_out, int out_size, void* d_ws, size_t ws_size,
                              hipStream_t stream)
{
    const float* x      = (const float*)d_in[0];
    const float* in_w   = (const float*)d_in[1];
    const float* in_b   = (const float*)d_in[2];
    const float* W_xz   = (const float*)d_in[3];
    const float* conv_w = (const float*)d_in[4];
    const float* conv_b = (const float*)d_in[5];
    const float* W_xp   = (const float*)d_in[6];
    const float* W_dt   = (const float*)d_in[7];
    const float* b_dt   = (const float*)d_in[8];
    const float* A_log  = (const float*)d_in[9];
    const float* D_par  = (const float*)d_in[10];
    const float* W_out  = (const float*)d_in[11];
    const float* ln_g   = (const float*)d_in[12];
    const float* ln_b   = (const float*)d_in[13];
    float* out = (float*)d_out;

    // Workspace layout (floats): 93.3 MB total, same as before.
    float* ws   = (float*)d_ws;
    float* h    = ws;                             // 4096*512   (2,097,152)
    float* xz   = h    + (size_t)MTOT*DMODEL;     // 4096*2048
    float* u    = xz   + (size_t)MTOT*2*DINNER;   // 4096*1024
    float* xdbl = u    + (size_t)MTOT*DINNER;     // 4096*64
    float* dt   = xdbl + (size_t)MTOT*64;         // 4096*1024
    float* y    = dt   + (size_t)MTOT*DINNER;     // 4096*1024
    // Scan chunk-state buffers alias the (dead-between-GEMMs) h region:
    //   hfinal/cumA each B_*CHUNKS*DINNER*DSTATE = 1,048,576 floats -> 2 fit in h.
    float* hfinal = h;
    float* cumA   = h + (size_t)B_*CHUNKS*DINNER*DSTATE;
    // x-proj K-split partials (4 x 1,048,576 floats) alias y (dead until scan3).
    float* xpart  = y;

    in_proj_kernel<<<MTOT*DMODEL/256, 256, 0, stream>>>(x, in_w, in_b, h);

    for (int layer = 0; layer < DEPTH_; ++layer) {
        const float* Wxz  = W_xz   + (size_t)layer * 2048 * DMODEL;
        const float* cw   = conv_w + (size_t)layer * DINNER * DCONV;
        const float* cb   = conv_b + (size_t)layer * DINNER;
        const float* Wxp  = W_xp   + (size_t)layer * 64 * DINNER;
        const float* Wdt  = W_dt   + (size_t)layer * DINNER * DTRANK;
        const float* bdt  = b_dt   + (size_t)layer * DINNER;
        const float* Alog = A_log  + (size_t)layer * DINNER * DSTATE;
        const float* Dp   = D_par  + (size_t)layer * DINNER;
        const float* Wout = W_out  + (size_t)layer * DMODEL * DINNER;

        // xz = h @ Wxz^T : (4096 x 2048), K=512
        gemm_nt128<<<dim3(2048/128, MTOT/128), 256, 0, stream>>>(h, DMODEL, Wxz, DMODEL, xz, 2048, DMODEL);
        // u = silu(conv(xc) + cb)
        conv_silu_kernel<<<MTOT*DINNER/256, 256, 0, stream>>>(xz, cw, cb, u);
        // xdbl = u @ Wxp^T : (4096 x 64), K=1024 — K-split x4 + reduce
        xp_kernel<<<dim3(4, MTOT/16), 256, 0, stream>>>(u, Wxp, xpart);
        xpsum_kernel<<<(MTOT*64/4)/256, 256, 0, stream>>>(xpart, xdbl);
        // dt = softplus(dt_lr @ Wdt^T + b_dt)
        dt_kernel<<<MTOT/8, 256, 0, stream>>>(xdbl, Wdt, bdt, dt);
        // chunked selective scan
        scan1_kernel<<<(B_*DINNER*CHUNKS)/16, 256, 0, stream>>>(u, xdbl, dt, Alog, hfinal, cumA);
        scan2_kernel<<<(B_*DINNER*DSTATE)/256, 256, 0, stream>>>(hfinal, cumA);
        scan3_kernel<<<(B_*DINNER*CHUNKS)/16, 256, 0, stream>>>(xz, u, xdbl, dt, Alog, Dp, hfinal, y);
        // h = y @ Wout^T : (4096 x 512), K=1024 — 64-tile for 512 blocks
        gemm_nt64<<<dim3(DMODEL/64, MTOT/64), 256, 0, stream>>>(y, DINNER, Wout, DINNER, h, DMODEL, DINNER);
    }

    ln_kernel<<<MTOT, 256, 0, stream>>>(h, ln_g, ln_b, out);
}

// Round 4
// 1058.679 us; speedup vs baseline: 3.5114x; 1.3955x over previous
//
#include <hip/hip_runtime.h>
#include <math.h>

// Problem constants (match reference)
#define B_      4
#define L_      1024
#define D_INNC  8      // D_IN
#define DMODEL  512
#define DEPTH_  4
#define DINNER  1024
#define DSTATE  16
#define DCONV   4
#define DTRANK  32
#define MTOT    (B_*L_)   // 4096
#define CHUNKS  16
#define CLEN    64        // L_/CHUNKS

typedef float f32x4 __attribute__((ext_vector_type(4)));
typedef short s16x8 __attribute__((ext_vector_type(8)));

// ---------------------------------------------------------------------------
// h = x @ in_w^T + in_b    (4096 x 512, K=8)
__global__ __launch_bounds__(256) void in_proj_kernel(
    const float* __restrict__ x, const float* __restrict__ w,
    const float* __restrict__ bias, float* __restrict__ h)
{
    int idx = blockIdx.x * 256 + threadIdx.x;      // over MTOT*DMODEL
    int m = idx / DMODEL, d = idx % DMODEL;
    const float* xr = x + m * D_INNC;
    const float* wr = w + d * D_INNC;
    float acc = bias[d];
#pragma unroll
    for (int k = 0; k < D_INNC; ++k) acc += xr[k] * wr[k];
    h[idx] = acc;
}

// ---------------------------------------------------------------------------
// Split-bf16 MFMA NT GEMM: C[m,n] = sum_k A[m,k]*B[n,k], fp32 in/out.
// BM=128, BK=32, 256 threads (4 waves, 2x2), wave tile 64 x (BN/2).
// Each fp32 is split x = hi + lo (bf16 each); D = ah*bh + ah*bl + al*bh.
// Fragment layouts (gfx950, m89-verified):
//   A/B operand: [idx = lane&15][k = (lane>>4)*8 + j]  (8 bf16 = 1 ds_read_b128)
//   C/D: col = lane&15, row = (lane>>4)*4 + reg
template<int BN>
__global__ __launch_bounds__(256) void gemm_nt_mfma(
    const float* __restrict__ A, int lda,
    const float* __restrict__ B, int ldb,
    float* __restrict__ C, int ldc, int K)
{
    constexpr int BM = 128;
    constexpr int FN = BN / 32;          // B fragments per wave
    __shared__ __align__(16) short Ah[4][BM][8], Al[4][BM][8];
    __shared__ __align__(16) short Bh[4][BN][8], Bl[4][BN][8];

    const int t    = threadIdx.x;
    const int lane = t & 63;
    const int w    = t >> 6;
    const int wm   = (w >> 1) * 64;        // wave m-offset in tile
    const int wn   = (w & 1) * (BN / 2);   // wave n-offset in tile
    const int quad = lane >> 4;
    const int l16  = lane & 15;
    const int m0   = blockIdx.y * BM;
    const int n0   = blockIdx.x * BN;

    f32x4 acc[4][FN];
#pragma unroll
    for (int i = 0; i < 4; ++i)
#pragma unroll
        for (int j = 0; j < FN; ++j) acc[i][j] = (f32x4){0.f, 0.f, 0.f, 0.f};

    for (int k0 = 0; k0 < K; k0 += 32) {
        __syncthreads();
        // ---- stage A tile (BM x 32 fp32 -> hi/lo bf16), coalesced ----
#pragma unroll
        for (int c = 0; c < (BM * 4) / 256; ++c) {
            int id  = c * 256 + t;           // (row, kblock)
            int row = id >> 2, kb = id & 3;
            const float* src = A + (size_t)(m0 + row) * lda + k0 + kb * 8;
            float4 f0 = *(const float4*)src;
            float4 f1 = *(const float4*)(src + 4);
            float f[8] = {f0.x,f0.y,f0.z,f0.w,f1.x,f1.y,f1.z,f1.w};
            s16x8 hi, lo;
#pragma unroll
            for (int i = 0; i < 8; ++i) {
                unsigned bb = __float_as_uint(f[i]);
                hi[i] = (short)(bb >> 16);
                float l = f[i] - __uint_as_float(bb & 0xFFFF0000u);
                lo[i] = (short)(__float_as_uint(l) >> 16);
            }
            *(s16x8*)&Ah[kb][row][0] = hi;
            *(s16x8*)&Al[kb][row][0] = lo;
        }
        // ---- stage B tile (BN x 32 fp32 -> hi/lo bf16) ----
#pragma unroll
        for (int c = 0; c < (BN * 4) / 256; ++c) {
            int id  = c * 256 + t;
            int row = id >> 2, kb = id & 3;
            const float* src = B + (size_t)(n0 + row) * ldb + k0 + kb * 8;
            float4 f0 = *(const float4*)src;
            float4 f1 = *(const float4*)(src + 4);
            float f[8] = {f0.x,f0.y,f0.z,f0.w,f1.x,f1.y,f1.z,f1.w};
            s16x8 hi, lo;
#pragma unroll
            for (int i = 0; i < 8; ++i) {
                unsigned bb = __float_as_uint(f[i]);
                hi[i] = (short)(bb >> 16);
                float l = f[i] - __uint_as_float(bb & 0xFFFF0000u);
                lo[i] = (short)(__float_as_uint(l) >> 16);
            }
            *(s16x8*)&Bh[kb][row][0] = hi;
            *(s16x8*)&Bl[kb][row][0] = lo;
        }
        __syncthreads();

        // ---- fragments + MFMA ----
        s16x8 afh[4], afl[4], bfh[FN], bfl[FN];
#pragma unroll
        for (int i = 0; i < 4; ++i) {
            int r = wm + i * 16 + l16;
            afh[i] = *(const s16x8*)&Ah[quad][r][0];
            afl[i] = *(const s16x8*)&Al[quad][r][0];
        }
#pragma unroll
        for (int j = 0; j < FN; ++j) {
            int r = wn + j * 16 + l16;
            bfh[j] = *(const s16x8*)&Bh[quad][r][0];
            bfl[j] = *(const s16x8*)&Bl[quad][r][0];
        }
#pragma unroll
        for (int i = 0; i < 4; ++i)
#pragma unroll
            for (int j = 0; j < FN; ++j) {
                acc[i][j] = __builtin_amdgcn_mfma_f32_16x16x32_bf16(afl[i], bfh[j], acc[i][j], 0, 0, 0);
                acc[i][j] = __builtin_amdgcn_mfma_f32_16x16x32_bf16(afh[i], bfl[j], acc[i][j], 0, 0, 0);
                acc[i][j] = __builtin_amdgcn_mfma_f32_16x16x32_bf16(afh[i], bfh[j], acc[i][j], 0, 0, 0);
            }
    }

    // ---- epilogue: C/D layout col=lane&15, row=quad*4+reg ----
#pragma unroll
    for (int i = 0; i < 4; ++i)
#pragma unroll
        for (int j = 0; j < FN; ++j) {
            int col = n0 + wn + j * 16 + l16;
#pragma unroll
            for (int r = 0; r < 4; ++r) {
                int rowc = m0 + wm + i * 16 + quad * 4 + r;
                C[(size_t)rowc * ldc + col] = acc[i][j][r];
            }
        }
}

// ---------------------------------------------------------------------------
// Depthwise causal conv (k=4) + bias + SiLU. Reads xc = xz[:, 0:1024].
__global__ __launch_bounds__(256) void conv_silu_kernel(
    const float* __restrict__ xz, const float* __restrict__ cw,
    const float* __restrict__ cb, float* __restrict__ u)
{
    int idx = blockIdx.x * 256 + threadIdx.x;   // MTOT*DINNER
    int m = idx >> 10;
    int d = idx & (DINNER - 1);
    int l = m & (L_ - 1);

    const float4 w = *(const float4*)&cw[d * 4];
    float acc = cb[d];
    if (l >= 3) acc += xz[(size_t)(m-3) * 2048 + d] * w.x;
    if (l >= 2) acc += xz[(size_t)(m-2) * 2048 + d] * w.y;
    if (l >= 1) acc += xz[(size_t)(m-1) * 2048 + d] * w.z;
    acc             += xz[(size_t)m     * 2048 + d] * w.w;
    u[idx] = acc / (1.f + __expf(-acc));   // silu
}

// ---------------------------------------------------------------------------
// x-proj partial GEMM: part[p][m][n] = sum_{k in split p} u[m,k]*W[n,k]
// BM=16, N=64, K-split 4x256. grid (4, 256).
__global__ __launch_bounds__(256) void xp_kernel(
    const float* __restrict__ u, const float* __restrict__ W,
    float* __restrict__ part)
{
    __shared__ float As[16][68];
    __shared__ float Ws[64][65];
    const int p  = blockIdx.x;
    const int m0 = blockIdx.y * 16;
    const int t  = threadIdx.x;
    const int kb = p * 256;
    const int n  = t & 63;
    const int mi = t >> 6;
    float acc[4] = {0.f, 0.f, 0.f, 0.f};

    for (int kt = 0; kt < 256; kt += 64) {
        const int k0 = kb + kt;
        __syncthreads();
        {   // stage A tile 16x64
            int r = t >> 4, cc = t & 15;
            float4 v = *(const float4*)&u[(size_t)(m0 + r) * DINNER + k0 + cc*4];
            As[r][cc*4+0] = v.x; As[r][cc*4+1] = v.y; As[r][cc*4+2] = v.z; As[r][cc*4+3] = v.w;
        }
        {   // stage W tile 64x64
            int r = t >> 2, f = t & 3;
#pragma unroll
            for (int q = 0; q < 4; ++q) {
                float4 v = *(const float4*)&W[(size_t)r * DINNER + k0 + f*16 + q*4];
                Ws[r][f*16+q*4+0] = v.x; Ws[r][f*16+q*4+1] = v.y;
                Ws[r][f*16+q*4+2] = v.z; Ws[r][f*16+q*4+3] = v.w;
            }
        }
        __syncthreads();
#pragma unroll 8
        for (int kk = 0; kk < 64; ++kk) {
            float w = Ws[n][kk];
#pragma unroll
            for (int j = 0; j < 4; ++j) acc[j] += As[mi*4+j][kk] * w;
        }
    }
#pragma unroll
    for (int j = 0; j < 4; ++j)
        part[((size_t)p * MTOT + m0 + mi*4 + j) * 64 + n] = acc[j];
}

// Sum the 4 K-split partials -> xdbl. float4 over MTOT*64 floats.
__global__ __launch_bounds__(256) void xpsum_kernel(
    const float* __restrict__ part, float* __restrict__ xdbl)
{
    int i = blockIdx.x * 256 + threadIdx.x;          // MTOT*64/4 = 65536
    const size_t stride = (size_t)MTOT * 64 / 4;
    const float4* p = (const float4*)part;
    float4 a = p[i], b = p[i + stride], c = p[i + 2*stride], d = p[i + 3*stride];
    float4 o = make_float4(a.x+b.x+c.x+d.x, a.y+b.y+c.y+d.y,
                           a.z+b.z+c.z+d.z, a.w+b.w+c.w+d.w);
    ((float4*)xdbl)[i] = o;
}

// ---------------------------------------------------------------------------
// dt = softplus(dt_lr @ Wdt^T + b_dt); 8 rows of m per block (reuse Wdt).
__global__ __launch_bounds__(256) void dt_kernel(
    const float* __restrict__ xdbl, const float* __restrict__ Wdt,
    const float* __restrict__ bdt, float* __restrict__ dt)
{
    __shared__ float a[8][DTRANK];
    const int m0 = blockIdx.x * 8;
    const int t = threadIdx.x;
    if (t < 8 * DTRANK) a[t >> 5][t & 31] = xdbl[(size_t)(m0 + (t >> 5)) * 64 + (t & 31)];
    __syncthreads();
    for (int n = t; n < DINNER; n += 256) {
        const float* w = Wdt + (size_t)n * DTRANK;
        float bb = bdt[n];
        float acc[8];
#pragma unroll
        for (int r = 0; r < 8; ++r) acc[r] = bb;
#pragma unroll
        for (int k = 0; k < DTRANK; ++k) {
            float wk = w[k];
#pragma unroll
            for (int r = 0; r < 8; ++r) acc[r] += a[r][k] * wk;
        }
#pragma unroll
        for (int r = 0; r < 8; ++r) {
            float v = acc[r];
            float sp = (v > 20.f) ? v : log1pf(expf(v));
            dt[(size_t)(m0 + r) * DINNER + n] = sp;
        }
    }
}

// ---------------------------------------------------------------------------
// Chunked selective scan, pass 1: per (b,d,chunk) local scan from h=0.
__global__ __launch_bounds__(256) void scan1_kernel(
    const float* __restrict__ u, const float* __restrict__ xdbl,
    const float* __restrict__ dt, const float* __restrict__ A_log,
    float* __restrict__ hfinal, float* __restrict__ cumA)
{
    const int s   = threadIdx.x & 15;
    const int g   = threadIdx.x >> 4;
    const int gid = blockIdx.x * 16 + g;
    const int d   = gid & (DINNER - 1);
    const int c   = (gid >> 10) & (CHUNKS - 1);
    const int b   = gid >> 14;

    const float Aval = -__expf(A_log[d * DSTATE + s]);
    float h = 0.f, cum = 1.f;
    const int mbase = b * L_ + c * CLEN;

    for (int t0 = 0; t0 < CLEN; t0 += 8) {
        float dt8[8], u8[8], B8[8];
#pragma unroll
        for (int j = 0; j < 8; ++j) {
            int m = mbase + t0 + j;
            dt8[j] = dt[(size_t)m * DINNER + d];
            u8[j]  = u [(size_t)m * DINNER + d];
            B8[j]  = xdbl[(size_t)m * 64 + 32 + s];
        }
#pragma unroll
        for (int j = 0; j < 8; ++j) {
            float dA = __expf(dt8[j] * Aval);
            cum *= dA;
            h = dA * h + dt8[j] * B8[j] * u8[j];
        }
    }
    size_t idx = ((size_t)(b * CHUNKS + c) * DINNER + d) * DSTATE + s;
    hfinal[idx] = h;
    cumA[idx]   = cum;
}

// Pass 2: sequential chunk fix-up, in place: hfinal[c] <- h_start(c).
__global__ __launch_bounds__(256) void scan2_kernel(
    float* __restrict__ hfinal, const float* __restrict__ cumA)
{
    int t = blockIdx.x * 256 + threadIdx.x;   // 65536 = B_*DINNER*DSTATE
    int s = t & 15, d = (t >> 4) & (DINNER - 1), b = t >> 14;
    float h = 0.f;
    for (int c = 0; c < CHUNKS; ++c) {
        size_t idx = ((size_t)(b * CHUNKS + c) * DINNER + d) * DSTATE + s;
        float hf = hfinal[idx], cA = cumA[idx];
        hfinal[idx] = h;          // becomes h_start for chunk c
        h = cA * h + hf;
    }
}

// Pass 3: re-run local scan seeded with true h_start; fuse y = (C.h + u*D)*silu(z).
__global__ __launch_bounds__(256) void scan3_kernel(
    const float* __restrict__ xz, const float* __restrict__ u,
    const float* __restrict__ xdbl, const float* __restrict__ dt,
    const float* __restrict__ A_log, const float* __restrict__ Dp,
    const float* __restrict__ hstart, float* __restrict__ y)
{
    const int s   = threadIdx.x & 15;
    const int g   = threadIdx.x >> 4;
    const int gid = blockIdx.x * 16 + g;
    const int d   = gid & (DINNER - 1);
    const int c   = (gid >> 10) & (CHUNKS - 1);
    const int b   = gid >> 14;

    const float Aval = -__expf(A_log[d * DSTATE + s]);
    const float Dval = Dp[d];
    size_t sidx = ((size_t)(b * CHUNKS + c) * DINNER + d) * DSTATE + s;
    float hst = hstart[sidx];
    const int mbase = b * L_ + c * CLEN;

    for (int t0 = 0; t0 < CLEN; t0 += 8) {
        float dt8[8], u8[8], B8[8], C8[8], z8[8];
#pragma unroll
        for (int j = 0; j < 8; ++j) {
            int m = mbase + t0 + j;
            dt8[j] = dt[(size_t)m * DINNER + d];
            u8[j]  = u [(size_t)m * DINNER + d];
            B8[j]  = xdbl[(size_t)m * 64 + 32 + s];
            C8[j]  = xdbl[(size_t)m * 64 + 48 + s];
            z8[j]  = xz[(size_t)m * 2048 + DINNER + d];
        }
        float part8[8];
#pragma unroll
        for (int j = 0; j < 8; ++j) {
            float dtv = dt8[j];
            float dA  = __expf(dtv * Aval);
            hst = dA * hst + dtv * B8[j] * u8[j];
            part8[j] = hst * C8[j];
        }
#pragma unroll
        for (int off = 8; off; off >>= 1) {
#pragma unroll
            for (int j = 0; j < 8; ++j)
                part8[j] += __shfl_xor(part8[j], off);
        }
        if (s == 0) {
#pragma unroll
            for (int j = 0; j < 8; ++j) {
                int m = mbase + t0 + j;
                float zv = z8[j];
                float sz = zv / (1.f + __expf(-zv));
                y[(size_t)m * DINNER + d] = (part8[j] + u8[j] * Dval) * sz;
            }
        }
    }
}

// ---------------------------------------------------------------------------
// Final LayerNorm over DMODEL=512.
__global__ __launch_bounds__(256) void ln_kernel(
    const float* __restrict__ h, const float* __restrict__ g,
    const float* __restrict__ bta, float* __restrict__ out)
{
    int m = blockIdx.x;
    const float* row = h + (size_t)m * DMODEL;
    int t = threadIdx.x;
    float v0 = row[t], v1 = row[t + 256];
    float sum = v0 + v1, sq = v0*v0 + v1*v1;
#pragma unroll
    for (int off = 32; off; off >>= 1) {
        sum += __shfl_down(sum, off);
        sq  += __shfl_down(sq,  off);
    }
    __shared__ float ls[4], lq[4];
    int w = t >> 6;
    if ((t & 63) == 0) { ls[w] = sum; lq[w] = sq; }
    __syncthreads();
    sum = ls[0] + ls[1] + ls[2] + ls[3];
    sq  = lq[0] + lq[1] + lq[2] + lq[3];
    float mu  = sum * (1.f / DMODEL);
    float var = sq * (1.f / DMODEL) - mu * mu;
    float rs  = rsqrtf(var + 1e-5f);
    out[(size_t)m * DMODEL + t]       = (v0 - mu) * rs * g[t]       + bta[t];
    out[(size_t)m * DMODEL + t + 256] = (v1 - mu) * rs * g[t + 256] + bta[t + 256];
}

// ---------------------------------------------------------------------------
extern "C" void kernel_launch(void* const* d_in, const int* in_sizes, int n_in,
                              void* d_out, int out_size, void* d_ws, size_t ws_size,
                              hipStream_t stream)
{
    const float* x      = (const float*)d_in[0];
    const float* in_w   = (const float*)d_in[1];
    const float* in_b   = (const float*)d_in[2];
    const float* W_xz   = (const float*)d_in[3];
    const float* conv_w = (const float*)d_in[4];
    const float* conv_b = (const float*)d_in[5];
    const float* W_xp   = (const float*)d_in[6];
    const float* W_dt   = (const float*)d_in[7];
    const float* b_dt   = (const float*)d_in[8];
    const float* A_log  = (const float*)d_in[9];
    const float* D_par  = (const float*)d_in[10];
    const float* W_out  = (const float*)d_in[11];
    const float* ln_g   = (const float*)d_in[12];
    const float* ln_b   = (const float*)d_in[13];
    float* out = (float*)d_out;

    // Workspace layout (floats): 93.3 MB total.
    float* ws   = (float*)d_ws;
    float* h    = ws;                             // 4096*512
    float* xz   = h    + (size_t)MTOT*DMODEL;     // 4096*2048
    float* u    = xz   + (size_t)MTOT*2*DINNER;   // 4096*1024
    float* xdbl = u    + (size_t)MTOT*DINNER;     // 4096*64
    float* dt   = xdbl + (size_t)MTOT*64;         // 4096*1024
    float* y    = dt   + (size_t)MTOT*DINNER;     // 4096*1024
    // Scan chunk-state buffers alias the (dead-between-GEMMs) h region.
    float* hfinal = h;
    float* cumA   = h + (size_t)B_*CHUNKS*DINNER*DSTATE;
    // x-proj K-split partials alias y (dead until scan3).
    float* xpart  = y;

    in_proj_kernel<<<MTOT*DMODEL/256, 256, 0, stream>>>(x, in_w, in_b, h);

    for (int layer = 0; layer < DEPTH_; ++layer) {
        const float* Wxz  = W_xz   + (size_t)layer * 2048 * DMODEL;
        const float* cw   = conv_w + (size_t)layer * DINNER * DCONV;
        const float* cb   = conv_b + (size_t)layer * DINNER;
        const float* Wxp  = W_xp   + (size_t)layer * 64 * DINNER;
        const float* Wdt  = W_dt   + (size_t)layer * DINNER * DTRANK;
        const float* bdt  = b_dt   + (size_t)layer * DINNER;
        const float* Alog = A_log  + (size_t)layer * DINNER * DSTATE;
        const float* Dp   = D_par  + (size_t)layer * DINNER;
        const float* Wout = W_out  + (size_t)layer * DMODEL * DINNER;

        // xz = h @ Wxz^T : (4096 x 2048), K=512 — split-bf16 MFMA
        gemm_nt_mfma<128><<<dim3(2048/128, MTOT/128), 256, 0, stream>>>(h, DMODEL, Wxz, DMODEL, xz, 2048, DMODEL);
        // u = silu(conv(xc) + cb)
        conv_silu_kernel<<<MTOT*DINNER/256, 256, 0, stream>>>(xz, cw, cb, u);
        // xdbl = u @ Wxp^T : (4096 x 64), K=1024 — K-split x4 + reduce
        xp_kernel<<<dim3(4, MTOT/16), 256, 0, stream>>>(u, Wxp, xpart);
        xpsum_kernel<<<(MTOT*64/4)/256, 256, 0, stream>>>(xpart, xdbl);
        // dt = softplus(dt_lr @ Wdt^T + b_dt)
        dt_kernel<<<MTOT/8, 256, 0, stream>>>(xdbl, Wdt, bdt, dt);
        // chunked selective scan
        scan1_kernel<<<(B_*DINNER*CHUNKS)/16, 256, 0, stream>>>(u, xdbl, dt, Alog, hfinal, cumA);
        scan2_kernel<<<(B_*DINNER*DSTATE)/256, 256, 0, stream>>>(hfinal, cumA);
        scan3_kernel<<<(B_*DINNER*CHUNKS)/16, 256, 0, stream>>>(xz, u, xdbl, dt, Alog, Dp, hfinal, y);
        // h = y @ Wout^T : (4096 x 512), K=1024 — split-bf16 MFMA, BN=64 for 256 blocks
        gemm_nt_mfma<64><<<dim3(DMODEL/64, MTOT/128), 256, 0, stream>>>(y, DINNER, Wout, DINNER, h, DMODEL, DINNER);
    }

    ln_kernel<<<MTOT, 256, 0, stream>>>(h, ln_g, ln_b, out);
}

// Round 5
// 877.730 us; speedup vs baseline: 4.2353x; 1.2062x over previous
//
#include <hip/hip_runtime.h>
#include <math.h>

// Problem constants (match reference)
#define B_      4
#define L_      1024
#define D_INNC  8      // D_IN
#define DMODEL  512
#define DEPTH_  4
#define DINNER  1024
#define DSTATE  16
#define DCONV   4
#define DTRANK  32
#define MTOT    (B_*L_)   // 4096
#define CHUNKS  32
#define CLEN    32        // L_/CHUNKS

typedef float f32x4 __attribute__((ext_vector_type(4)));
typedef short s16x8 __attribute__((ext_vector_type(8)));

// ---------------------------------------------------------------------------
// h = x @ in_w^T + in_b    (4096 x 512, K=8)
__global__ __launch_bounds__(256) void in_proj_kernel(
    const float* __restrict__ x, const float* __restrict__ w,
    const float* __restrict__ bias, float* __restrict__ h)
{
    int idx = blockIdx.x * 256 + threadIdx.x;      // over MTOT*DMODEL
    int m = idx / DMODEL, d = idx % DMODEL;
    const float* xr = x + m * D_INNC;
    const float* wr = w + d * D_INNC;
    float acc = bias[d];
#pragma unroll
    for (int k = 0; k < D_INNC; ++k) acc += xr[k] * wr[k];
    h[idx] = acc;
}

// ---------------------------------------------------------------------------
// Split-bf16 MFMA NT GEMM: C[m,n] = sum_k A[m,k]*B[n,k], fp32 in/out.
// BM=128, BK=32, 256 threads (4 waves, 2x2), wave tile 64 x (BN/2).
// x = hi + lo (bf16 each); D = ah*bh + ah*bl + al*bh.
template<int BN>
__global__ __launch_bounds__(256) void gemm_nt_mfma(
    const float* __restrict__ A, int lda,
    const float* __restrict__ B, int ldb,
    float* __restrict__ C, int ldc, int K)
{
    constexpr int BM = 128;
    constexpr int FN = BN / 32;          // B fragments per wave
    __shared__ __align__(16) short Ah[4][BM][8], Al[4][BM][8];
    __shared__ __align__(16) short Bh[4][BN][8], Bl[4][BN][8];

    const int t    = threadIdx.x;
    const int lane = t & 63;
    const int w    = t >> 6;
    const int wm   = (w >> 1) * 64;        // wave m-offset in tile
    const int wn   = (w & 1) * (BN / 2);   // wave n-offset in tile
    const int quad = lane >> 4;
    const int l16  = lane & 15;
    const int m0   = blockIdx.y * BM;
    const int n0   = blockIdx.x * BN;

    f32x4 acc[4][FN];
#pragma unroll
    for (int i = 0; i < 4; ++i)
#pragma unroll
        for (int j = 0; j < FN; ++j) acc[i][j] = (f32x4){0.f, 0.f, 0.f, 0.f};

    for (int k0 = 0; k0 < K; k0 += 32) {
        __syncthreads();
        // ---- stage A tile (BM x 32 fp32 -> hi/lo bf16), coalesced ----
#pragma unroll
        for (int c = 0; c < (BM * 4) / 256; ++c) {
            int id  = c * 256 + t;           // (row, kblock)
            int row = id >> 2, kb = id & 3;
            const float* src = A + (size_t)(m0 + row) * lda + k0 + kb * 8;
            float4 f0 = *(const float4*)src;
            float4 f1 = *(const float4*)(src + 4);
            float f[8] = {f0.x,f0.y,f0.z,f0.w,f1.x,f1.y,f1.z,f1.w};
            s16x8 hi, lo;
#pragma unroll
            for (int i = 0; i < 8; ++i) {
                unsigned bb = __float_as_uint(f[i]);
                hi[i] = (short)(bb >> 16);
                float l = f[i] - __uint_as_float(bb & 0xFFFF0000u);
                lo[i] = (short)(__float_as_uint(l) >> 16);
            }
            *(s16x8*)&Ah[kb][row][0] = hi;
            *(s16x8*)&Al[kb][row][0] = lo;
        }
        // ---- stage B tile (BN x 32 fp32 -> hi/lo bf16) ----
#pragma unroll
        for (int c = 0; c < (BN * 4) / 256; ++c) {
            int id  = c * 256 + t;
            int row = id >> 2, kb = id & 3;
            const float* src = B + (size_t)(n0 + row) * ldb + k0 + kb * 8;
            float4 f0 = *(const float4*)src;
            float4 f1 = *(const float4*)(src + 4);
            float f[8] = {f0.x,f0.y,f0.z,f0.w,f1.x,f1.y,f1.z,f1.w};
            s16x8 hi, lo;
#pragma unroll
            for (int i = 0; i < 8; ++i) {
                unsigned bb = __float_as_uint(f[i]);
                hi[i] = (short)(bb >> 16);
                float l = f[i] - __uint_as_float(bb & 0xFFFF0000u);
                lo[i] = (short)(__float_as_uint(l) >> 16);
            }
            *(s16x8*)&Bh[kb][row][0] = hi;
            *(s16x8*)&Bl[kb][row][0] = lo;
        }
        __syncthreads();

        // ---- fragments + MFMA ----
        s16x8 afh[4], afl[4], bfh[FN], bfl[FN];
#pragma unroll
        for (int i = 0; i < 4; ++i) {
            int r = wm + i * 16 + l16;
            afh[i] = *(const s16x8*)&Ah[quad][r][0];
            afl[i] = *(const s16x8*)&Al[quad][r][0];
        }
#pragma unroll
        for (int j = 0; j < FN; ++j) {
            int r = wn + j * 16 + l16;
            bfh[j] = *(const s16x8*)&Bh[quad][r][0];
            bfl[j] = *(const s16x8*)&Bl[quad][r][0];
        }
#pragma unroll
        for (int i = 0; i < 4; ++i)
#pragma unroll
            for (int j = 0; j < FN; ++j) {
                acc[i][j] = __builtin_amdgcn_mfma_f32_16x16x32_bf16(afl[i], bfh[j], acc[i][j], 0, 0, 0);
                acc[i][j] = __builtin_amdgcn_mfma_f32_16x16x32_bf16(afh[i], bfl[j], acc[i][j], 0, 0, 0);
                acc[i][j] = __builtin_amdgcn_mfma_f32_16x16x32_bf16(afh[i], bfh[j], acc[i][j], 0, 0, 0);
            }
    }

    // ---- epilogue: C/D layout col=lane&15, row=quad*4+reg ----
#pragma unroll
    for (int i = 0; i < 4; ++i)
#pragma unroll
        for (int j = 0; j < FN; ++j) {
            int col = n0 + wn + j * 16 + l16;
#pragma unroll
            for (int r = 0; r < 4; ++r) {
                int rowc = m0 + wm + i * 16 + quad * 4 + r;
                C[(size_t)rowc * ldc + col] = acc[i][j][r];
            }
        }
}

// ---------------------------------------------------------------------------
// Depthwise causal conv (k=4) + bias + SiLU. Reads xc = xz[:, 0:1024].
__global__ __launch_bounds__(256) void conv_silu_kernel(
    const float* __restrict__ xz, const float* __restrict__ cw,
    const float* __restrict__ cb, float* __restrict__ u)
{
    int idx = blockIdx.x * 256 + threadIdx.x;   // MTOT*DINNER
    int m = idx >> 10;
    int d = idx & (DINNER - 1);
    int l = m & (L_ - 1);

    const float4 w = *(const float4*)&cw[d * 4];
    float acc = cb[d];
    if (l >= 3) acc += xz[(size_t)(m-3) * 2048 + d] * w.x;
    if (l >= 2) acc += xz[(size_t)(m-2) * 2048 + d] * w.y;
    if (l >= 1) acc += xz[(size_t)(m-1) * 2048 + d] * w.z;
    acc             += xz[(size_t)m     * 2048 + d] * w.w;
    u[idx] = acc / (1.f + __expf(-acc));   // silu
}

// ---------------------------------------------------------------------------
// x-proj partial GEMM: part[p][m][n] = sum_{k in split p} u[m,k]*W[n,k]
__global__ __launch_bounds__(256) void xp_kernel(
    const float* __restrict__ u, const float* __restrict__ W,
    float* __restrict__ part)
{
    __shared__ float As[16][68];
    __shared__ float Ws[64][65];
    const int p  = blockIdx.x;
    const int m0 = blockIdx.y * 16;
    const int t  = threadIdx.x;
    const int kb = p * 256;
    const int n  = t & 63;
    const int mi = t >> 6;
    float acc[4] = {0.f, 0.f, 0.f, 0.f};

    for (int kt = 0; kt < 256; kt += 64) {
        const int k0 = kb + kt;
        __syncthreads();
        {   // stage A tile 16x64
            int r = t >> 4, cc = t & 15;
            float4 v = *(const float4*)&u[(size_t)(m0 + r) * DINNER + k0 + cc*4];
            As[r][cc*4+0] = v.x; As[r][cc*4+1] = v.y; As[r][cc*4+2] = v.z; As[r][cc*4+3] = v.w;
        }
        {   // stage W tile 64x64
            int r = t >> 2, f = t & 3;
#pragma unroll
            for (int q = 0; q < 4; ++q) {
                float4 v = *(const float4*)&W[(size_t)r * DINNER + k0 + f*16 + q*4];
                Ws[r][f*16+q*4+0] = v.x; Ws[r][f*16+q*4+1] = v.y;
                Ws[r][f*16+q*4+2] = v.z; Ws[r][f*16+q*4+3] = v.w;
            }
        }
        __syncthreads();
#pragma unroll 8
        for (int kk = 0; kk < 64; ++kk) {
            float w = Ws[n][kk];
#pragma unroll
            for (int j = 0; j < 4; ++j) acc[j] += As[mi*4+j][kk] * w;
        }
    }
#pragma unroll
    for (int j = 0; j < 4; ++j)
        part[((size_t)p * MTOT + m0 + mi*4 + j) * 64 + n] = acc[j];
}

// Sum the 4 K-split partials -> xdbl. float4 over MTOT*64 floats.
__global__ __launch_bounds__(256) void xpsum_kernel(
    const float* __restrict__ part, float* __restrict__ xdbl)
{
    int i = blockIdx.x * 256 + threadIdx.x;          // MTOT*64/4 = 65536
    const size_t stride = (size_t)MTOT * 64 / 4;
    const float4* p = (const float4*)part;
    float4 a = p[i], b = p[i + stride], c = p[i + 2*stride], d = p[i + 3*stride];
    float4 o = make_float4(a.x+b.x+c.x+d.x, a.y+b.y+c.y+d.y,
                           a.z+b.z+c.z+d.z, a.w+b.w+c.w+d.w);
    ((float4*)xdbl)[i] = o;
}

// ---------------------------------------------------------------------------
// dt = softplus(dt_lr @ Wdt^T + b_dt); 8 rows of m per block (reuse Wdt).
__global__ __launch_bounds__(256) void dt_kernel(
    const float* __restrict__ xdbl, const float* __restrict__ Wdt,
    const float* __restrict__ bdt, float* __restrict__ dt)
{
    __shared__ float a[8][DTRANK];
    const int m0 = blockIdx.x * 8;
    const int t = threadIdx.x;
    if (t < 8 * DTRANK) a[t >> 5][t & 31] = xdbl[(size_t)(m0 + (t >> 5)) * 64 + (t & 31)];
    __syncthreads();
    for (int n = t; n < DINNER; n += 256) {
        const float* w = Wdt + (size_t)n * DTRANK;
        float bb = bdt[n];
        float acc[8];
#pragma unroll
        for (int r = 0; r < 8; ++r) acc[r] = bb;
#pragma unroll
        for (int k = 0; k < DTRANK; ++k) {
            float wk = w[k];
#pragma unroll
            for (int r = 0; r < 8; ++r) acc[r] += a[r][k] * wk;
        }
#pragma unroll
        for (int r = 0; r < 8; ++r) {
            float v = acc[r];
            float sp = (v > 20.f) ? v : log1pf(expf(v));
            dt[(size_t)(m0 + r) * DINNER + n] = sp;
        }
    }
}

// ---------------------------------------------------------------------------
// Chunked scan pass 1 — register-state layout: one lane per (b,c,d), all 16
// states in VGPRs. Block = 256 consecutive d for fixed (b,c). No shuffles.
// Writes hfinal[b][c][d][s] (local final states) and per-chunk dt-sum
// (stuffed into the dead dt_lr columns 0..31 of xdbl).
__global__ __launch_bounds__(256) void scan1_kernel(
    const float* __restrict__ u, const float* xdbl,
    const float* __restrict__ dtp, const float* __restrict__ A_log,
    float* __restrict__ hfinal, float* dtsum_out)
{
    __shared__ float Bs[CLEN][16];
    const int blk  = blockIdx.x;              // b*128 + c*4 + dblk
    const int dblk = blk & 3;
    const int c    = (blk >> 2) & (CHUNKS - 1);
    const int b    = blk >> 7;
    const int d    = dblk * 256 + threadIdx.x;
    const int mbase = b * L_ + c * CLEN;

#pragma unroll
    for (int q = 0; q < 2; ++q) {             // stage B chunk (32x16)
        int idx = q * 256 + threadIdx.x;
        int tt = idx >> 4, ss = idx & 15;
        Bs[tt][ss] = xdbl[(size_t)(mbase + tt) * 64 + 32 + ss];
    }
    float A[16];
    {
        float4 a4[4];
#pragma unroll
        for (int q = 0; q < 4; ++q) a4[q] = *(const float4*)&A_log[d * 16 + q * 4];
        const float* af = (const float*)a4;
#pragma unroll
        for (int s = 0; s < 16; ++s) A[s] = -__expf(af[s]);
    }
    __syncthreads();

    float h[16];
#pragma unroll
    for (int s = 0; s < 16; ++s) h[s] = 0.f;
    float dts = 0.f;

    for (int t0 = 0; t0 < CLEN; t0 += 8) {
        float dt8[8], u8[8];
#pragma unroll
        for (int j = 0; j < 8; ++j) {
            int m = mbase + t0 + j;
            dt8[j] = dtp[(size_t)m * DINNER + d];
            u8[j]  = u [(size_t)m * DINNER + d];
        }
#pragma unroll
        for (int j = 0; j < 8; ++j) {
            float dtv = dt8[j], dtu = dtv * u8[j];
            dts += dtv;
            float Bt[16];
#pragma unroll
            for (int q = 0; q < 4; ++q)
                *(float4*)&Bt[q*4] = *(const float4*)&Bs[t0 + j][q*4];
#pragma unroll
            for (int s = 0; s < 16; ++s) {
                float dA = __expf(dtv * A[s]);
                h[s] = dA * h[s] + dtu * Bt[s];
            }
        }
    }
    size_t base = ((size_t)(b * CHUNKS + c) * DINNER + d) * 16;
#pragma unroll
    for (int q = 0; q < 4; ++q)
        *(float4*)&hfinal[base + q*4] = make_float4(h[q*4], h[q*4+1], h[q*4+2], h[q*4+3]);
    int i = (b * CHUNKS + c) * DINNER + d;
    dtsum_out[(i >> 5) * 64 + (i & 31)] = dts;   // dead dt_lr cols of xdbl
}

// Pass 2: sequential chunk fix-up. Thread per (b,d,s); 8-batched prefetch.
// hfinal[c] <- true start state of chunk c; decay = exp(A_s * dtsum_c).
__global__ __launch_bounds__(256) void scan2_kernel(
    float* __restrict__ hfinal, const float* __restrict__ dtsum,
    const float* __restrict__ A_log)
{
    int t = blockIdx.x * 256 + threadIdx.x;   // 65536 = B_*DINNER*DSTATE
    int s = t & 15, d = (t >> 4) & (DINNER - 1), b = t >> 14;
    float As = -__expf(A_log[d * DSTATE + s]);
    float h = 0.f;
    for (int c0 = 0; c0 < CHUNKS; c0 += 8) {
        float hf8[8], dts8[8];
#pragma unroll
        for (int j = 0; j < 8; ++j) {
            int c = c0 + j;
            int i = (b * CHUNKS + c) * DINNER + d;
            dts8[j] = dtsum[(i >> 5) * 64 + (i & 31)];
            hf8[j]  = hfinal[((size_t)i) * 16 + s];
        }
#pragma unroll
        for (int j = 0; j < 8; ++j) {
            int c = c0 + j;
            size_t idx = ((size_t)((b * CHUNKS + c) * DINNER + d)) * 16 + s;
            hfinal[idx] = h;                       // start state for chunk c
            h = __expf(As * dts8[j]) * h + hf8[j];
        }
    }
}

// Pass 3: re-run local scan seeded with true start state; fuse
// y = (C.h + u*D) * silu(z). Same register-state layout as pass 1.
__global__ __launch_bounds__(256) void scan3_kernel(
    const float* __restrict__ xz, const float* __restrict__ u,
    const float* xdbl, const float* __restrict__ dtp,
    const float* __restrict__ A_log, const float* __restrict__ Dp,
    const float* __restrict__ hstart, float* __restrict__ y)
{
    __shared__ float Bs[CLEN][16];
    __shared__ float Cs[CLEN][16];
    const int blk  = blockIdx.x;
    const int dblk = blk & 3;
    const int c    = (blk >> 2) & (CHUNKS - 1);
    const int b    = blk >> 7;
    const int d    = dblk * 256 + threadIdx.x;
    const int mbase = b * L_ + c * CLEN;

#pragma unroll
    for (int q = 0; q < 2; ++q) {
        int idx = q * 256 + threadIdx.x;
        int tt = idx >> 4, ss = idx & 15;
        Bs[tt][ss] = xdbl[(size_t)(mbase + tt) * 64 + 32 + ss];
        Cs[tt][ss] = xdbl[(size_t)(mbase + tt) * 64 + 48 + ss];
    }
    float A[16];
    {
        float4 a4[4];
#pragma unroll
        for (int q = 0; q < 4; ++q) a4[q] = *(const float4*)&A_log[d * 16 + q * 4];
        const float* af = (const float*)a4;
#pragma unroll
        for (int s = 0; s < 16; ++s) A[s] = -__expf(af[s]);
    }
    const float Dval = Dp[d];

    float h[16];
    {
        size_t base = ((size_t)(b * CHUNKS + c) * DINNER + d) * 16;
#pragma unroll
        for (int q = 0; q < 4; ++q) {
            float4 v = *(const float4*)&hstart[base + q*4];
            h[q*4] = v.x; h[q*4+1] = v.y; h[q*4+2] = v.z; h[q*4+3] = v.w;
        }
    }
    __syncthreads();

    for (int t0 = 0; t0 < CLEN; t0 += 8) {
        float dt8[8], u8[8], z8[8];
#pragma unroll
        for (int j = 0; j < 8; ++j) {
            int m = mbase + t0 + j;
            dt8[j] = dtp[(size_t)m * DINNER + d];
            u8[j]  = u [(size_t)m * DINNER + d];
            z8[j]  = xz[(size_t)m * 2048 + DINNER + d];
        }
#pragma unroll
        for (int j = 0; j < 8; ++j) {
            float dtv = dt8[j], dtu = dtv * u8[j];
            float Bt[16], Ct[16];
#pragma unroll
            for (int q = 0; q < 4; ++q) {
                *(float4*)&Bt[q*4] = *(const float4*)&Bs[t0 + j][q*4];
                *(float4*)&Ct[q*4] = *(const float4*)&Cs[t0 + j][q*4];
            }
            float yv = 0.f;
#pragma unroll
            for (int s = 0; s < 16; ++s) {
                float dA = __expf(dtv * A[s]);
                h[s] = dA * h[s] + dtu * Bt[s];
                yv += h[s] * Ct[s];
            }
            float zv = z8[j];
            float sz = zv / (1.f + __expf(-zv));
            int m = mbase + t0 + j;
            y[(size_t)m * DINNER + d] = (yv + u8[j] * Dval) * sz;
        }
    }
}

// ---------------------------------------------------------------------------
// Final LayerNorm over DMODEL=512.
__global__ __launch_bounds__(256) void ln_kernel(
    const float* __restrict__ h, const float* __restrict__ g,
    const float* __restrict__ bta, float* __restrict__ out)
{
    int m = blockIdx.x;
    const float* row = h + (size_t)m * DMODEL;
    int t = threadIdx.x;
    float v0 = row[t], v1 = row[t + 256];
    float sum = v0 + v1, sq = v0*v0 + v1*v1;
#pragma unroll
    for (int off = 32; off; off >>= 1) {
        sum += __shfl_down(sum, off);
        sq  += __shfl_down(sq,  off);
    }
    __shared__ float ls[4], lq[4];
    int w = t >> 6;
    if ((t & 63) == 0) { ls[w] = sum; lq[w] = sq; }
    __syncthreads();
    sum = ls[0] + ls[1] + ls[2] + ls[3];
    sq  = lq[0] + lq[1] + lq[2] + lq[3];
    float mu  = sum * (1.f / DMODEL);
    float var = sq * (1.f / DMODEL) - mu * mu;
    float rs  = rsqrtf(var + 1e-5f);
    out[(size_t)m * DMODEL + t]       = (v0 - mu) * rs * g[t]       + bta[t];
    out[(size_t)m * DMODEL + t + 256] = (v1 - mu) * rs * g[t + 256] + bta[t + 256];
}

// ---------------------------------------------------------------------------
extern "C" void kernel_launch(void* const* d_in, const int* in_sizes, int n_in,
                              void* d_out, int out_size, void* d_ws, size_t ws_size,
                              hipStream_t stream)
{
    const float* x      = (const float*)d_in[0];
    const float* in_w   = (const float*)d_in[1];
    const float* in_b   = (const float*)d_in[2];
    const float* W_xz   = (const float*)d_in[3];
    const float* conv_w = (const float*)d_in[4];
    const float* conv_b = (const float*)d_in[5];
    const float* W_xp   = (const float*)d_in[6];
    const float* W_dt   = (const float*)d_in[7];
    const float* b_dt   = (const float*)d_in[8];
    const float* A_log  = (const float*)d_in[9];
    const float* D_par  = (const float*)d_in[10];
    const float* W_out  = (const float*)d_in[11];
    const float* ln_g   = (const float*)d_in[12];
    const float* ln_b   = (const float*)d_in[13];
    float* out = (float*)d_out;

    // Workspace layout (floats): 93.3 MB total (same as validated rounds).
    float* ws   = (float*)d_ws;
    float* h    = ws;                             // 4096*512 = 2,097,152
    float* xz   = h    + (size_t)MTOT*DMODEL;     // 4096*2048
    float* u    = xz   + (size_t)MTOT*2*DINNER;   // 4096*1024
    float* xdbl = u    + (size_t)MTOT*DINNER;     // 4096*64
    float* dt   = xdbl + (size_t)MTOT*64;         // 4096*1024
    float* y    = dt   + (size_t)MTOT*DINNER;     // 4096*1024
    // hfinal[b][c][d][s] = B_*CHUNKS*DINNER*DSTATE = 2,097,152 floats — exactly
    // the dead h region. Per-chunk dt-sums live in xdbl's dead dt_lr columns.
    float* hfinal = h;
    // x-proj K-split partials alias y (dead until scan3).
    float* xpart  = y;

    in_proj_kernel<<<MTOT*DMODEL/256, 256, 0, stream>>>(x, in_w, in_b, h);

    for (int layer = 0; layer < DEPTH_; ++layer) {
        const float* Wxz  = W_xz   + (size_t)layer * 2048 * DMODEL;
        const float* cw   = conv_w + (size_t)layer * DINNER * DCONV;
        const float* cb   = conv_b + (size_t)layer * DINNER;
        const float* Wxp  = W_xp   + (size_t)layer * 64 * DINNER;
        const float* Wdt  = W_dt   + (size_t)layer * DINNER * DTRANK;
        const float* bdt  = b_dt   + (size_t)layer * DINNER;
        const float* Alog = A_log  + (size_t)layer * DINNER * DSTATE;
        const float* Dp   = D_par  + (size_t)layer * DINNER;
        const float* Wout = W_out  + (size_t)layer * DMODEL * DINNER;

        // xz = h @ Wxz^T : (4096 x 2048), K=512 — split-bf16 MFMA
        gemm_nt_mfma<128><<<dim3(2048/128, MTOT/128), 256, 0, stream>>>(h, DMODEL, Wxz, DMODEL, xz, 2048, DMODEL);
        // u = silu(conv(xc) + cb)
        conv_silu_kernel<<<MTOT*DINNER/256, 256, 0, stream>>>(xz, cw, cb, u);
        // xdbl = u @ Wxp^T : (4096 x 64), K=1024 — K-split x4 + reduce
        xp_kernel<<<dim3(4, MTOT/16), 256, 0, stream>>>(u, Wxp, xpart);
        xpsum_kernel<<<(MTOT*64/4)/256, 256, 0, stream>>>(xpart, xdbl);
        // dt = softplus(dt_lr @ Wdt^T + b_dt)
        dt_kernel<<<MTOT/8, 256, 0, stream>>>(xdbl, Wdt, bdt, dt);
        // chunked selective scan (register-state layout)
        scan1_kernel<<<B_*CHUNKS*(DINNER/256), 256, 0, stream>>>(u, xdbl, dt, Alog, hfinal, xdbl);
        scan2_kernel<<<(B_*DINNER*DSTATE)/256, 256, 0, stream>>>(hfinal, xdbl, Alog);
        scan3_kernel<<<B_*CHUNKS*(DINNER/256), 256, 0, stream>>>(xz, u, xdbl, dt, Alog, Dp, hfinal, y);
        // h = y @ Wout^T : (4096 x 512), K=1024 — split-bf16 MFMA, BN=64
        gemm_nt_mfma<64><<<dim3(DMODEL/64, MTOT/128), 256, 0, stream>>>(y, DINNER, Wout, DINNER, h, DMODEL, DINNER);
    }

    ln_kernel<<<MTOT, 256, 0, stream>>>(h, ln_g, ln_b, out);
}

// Round 6
// 831.824 us; speedup vs baseline: 4.4690x; 1.0552x over previous
//
#include <hip/hip_runtime.h>
#include <math.h>

// Problem constants (match reference)
#define B_      4
#define L_      1024
#define D_INNC  8      // D_IN
#define DMODEL  512
#define DEPTH_  4
#define DINNER  1024
#define DSTATE  16
#define DCONV   4
#define DTRANK  32
#define MTOT    (B_*L_)   // 4096
#define CHUNKS  32
#define CLEN    32        // L_/CHUNKS

typedef float f32x4 __attribute__((ext_vector_type(4)));
typedef short s16x8 __attribute__((ext_vector_type(8)));
typedef unsigned short u16;
typedef unsigned short u16x4v __attribute__((ext_vector_type(4)));

// split fp32 -> hi/lo bf16 (truncation); hi+lo reconstructs to ~2^-16 rel.
__device__ __forceinline__ void split_bf16(float v, u16& hi, u16& lo) {
    unsigned bb = __float_as_uint(v);
    hi = (u16)(bb >> 16);
    float l = v - __uint_as_float(bb & 0xFFFF0000u);
    lo = (u16)(__float_as_uint(l) >> 16);
}
__device__ __forceinline__ float join_bf16(u16 hi, u16 lo) {
    return __uint_as_float((unsigned)hi << 16) + __uint_as_float((unsigned)lo << 16);
}

// ---------------------------------------------------------------------------
// h = x @ in_w^T + in_b  -> split pair (4096 x 512, K=8)
__global__ __launch_bounds__(256) void in_proj_kernel(
    const float* __restrict__ x, const float* __restrict__ w,
    const float* __restrict__ bias, u16* __restrict__ hh, u16* __restrict__ hl)
{
    int idx = blockIdx.x * 256 + threadIdx.x;
    int m = idx / DMODEL, d = idx % DMODEL;
    const float* xr = x + m * D_INNC;
    const float* wr = w + d * D_INNC;
    float acc = bias[d];
#pragma unroll
    for (int k = 0; k < D_INNC; ++k) acc += xr[k] * wr[k];
    u16 hi, lo; split_bf16(acc, hi, lo);
    hh[idx] = hi; hl[idx] = lo;
}

// ---------------------------------------------------------------------------
// Convert fp32 weight array -> hi/lo bf16 pair arrays. 8 elems/thread.
__global__ __launch_bounds__(256) void wconv_kernel(
    const float* __restrict__ W, u16* __restrict__ Wh, u16* __restrict__ Wl)
{
    int i = blockIdx.x * 256 + threadIdx.x;   // chunk of 8 elems
    const float* src = W + (size_t)i * 8;
    float4 f0 = *(const float4*)src;
    float4 f1 = *(const float4*)(src + 4);
    float f[8] = {f0.x,f0.y,f0.z,f0.w,f1.x,f1.y,f1.z,f1.w};
    s16x8 hv, lv;
#pragma unroll
    for (int e = 0; e < 8; ++e) {
        u16 hi, lo; split_bf16(f[e], hi, lo);
        hv[e] = (short)hi; lv[e] = (short)lo;
    }
    *(s16x8*)(Wh + (size_t)i * 8) = hv;
    *(s16x8*)(Wl + (size_t)i * 8) = lv;
}

// ---------------------------------------------------------------------------
// Pair-bf16 MFMA NT GEMM: C[m,n] = sum_k (Ah+Al)[m,k]*(Bh+Bl)[n,k] (3-term).
// BM=128, BK=32, 256 thr (4 waves 2x2), wave tile 64 x (BN/2).
// LDS k-planes padded by one 16B slot -> bank-even b128 reads/writes.
// blockIdx.z = K-split slice (length kLen); C += z*pstride.
template<int BN>
__global__ __launch_bounds__(256, 2) void gemm_pair(
    const u16* __restrict__ Ah, const u16* __restrict__ Al, int lda,
    const u16* __restrict__ Bh, const u16* __restrict__ Bl, int ldb,
    float* __restrict__ C, int ldc, int kLen, size_t pstride)
{
    constexpr int BM  = 128;
    constexpr int FN  = BN / 32;            // n-fragments per wave
    constexpr int ACH = 2;                  // A 16B-chunks per thread per array
    constexpr int BCH = (BN * 4) / 256;     // B chunks per thread per array
    __shared__ __align__(16) u16 AhS[4*(BM+1)*8], AlS[4*(BM+1)*8];
    __shared__ __align__(16) u16 BhS[4*(BN+1)*8], BlS[4*(BN+1)*8];

    const int t    = threadIdx.x;
    const int lane = t & 63;
    const int w    = t >> 6;
    const int wm   = (w >> 1) * 64;
    const int wn   = (w & 1) * (BN / 2);
    const int quad = lane >> 4;
    const int l16  = lane & 15;
    const int m0   = blockIdx.y * BM;
    const int n0   = blockIdx.x * BN;
    const int kstart = blockIdx.z * kLen;
    const int kend   = kstart + kLen;
    C += (size_t)blockIdx.z * pstride;

    f32x4 acc[4][FN];
#pragma unroll
    for (int i = 0; i < 4; ++i)
#pragma unroll
        for (int j = 0; j < FN; ++j) acc[i][j] = (f32x4){0.f,0.f,0.f,0.f};

    s16x8 rah[ACH], ral[ACH], rbh[BCH], rbl[BCH];
    // preload first K-slice
#pragma unroll
    for (int c = 0; c < ACH; ++c) {
        int id = c*256 + t, row = id >> 2, kb = id & 3;
        size_t g = (size_t)(m0 + row) * lda + kstart + kb*8;
        rah[c] = *(const s16x8*)(Ah + g);
        ral[c] = *(const s16x8*)(Al + g);
    }
#pragma unroll
    for (int c = 0; c < BCH; ++c) {
        int id = c*256 + t, row = id >> 2, kb = id & 3;
        size_t g = (size_t)(n0 + row) * ldb + kstart + kb*8;
        rbh[c] = *(const s16x8*)(Bh + g);
        rbl[c] = *(const s16x8*)(Bl + g);
    }

    for (int kk = kstart; kk < kend; kk += 32) {
        __syncthreads();
#pragma unroll
        for (int c = 0; c < ACH; ++c) {
            int id = c*256 + t, row = id >> 2, kb = id & 3;
            int slot = (kb*(BM+1) + row) * 8;
            *(s16x8*)&AhS[slot] = rah[c];
            *(s16x8*)&AlS[slot] = ral[c];
        }
#pragma unroll
        for (int c = 0; c < BCH; ++c) {
            int id = c*256 + t, row = id >> 2, kb = id & 3;
            int slot = (kb*(BN+1) + row) * 8;
            *(s16x8*)&BhS[slot] = rbh[c];
            *(s16x8*)&BlS[slot] = rbl[c];
        }
        __syncthreads();
        int kn = kk + 32;
        if (kn < kend) {   // prefetch next slice; overlaps the MFMA below
#pragma unroll
            for (int c = 0; c < ACH; ++c) {
                int id = c*256 + t, row = id >> 2, kb = id & 3;
                size_t g = (size_t)(m0 + row) * lda + kn + kb*8;
                rah[c] = *(const s16x8*)(Ah + g);
                ral[c] = *(const s16x8*)(Al + g);
            }
#pragma unroll
            for (int c = 0; c < BCH; ++c) {
                int id = c*256 + t, row = id >> 2, kb = id & 3;
                size_t g = (size_t)(n0 + row) * ldb + kn + kb*8;
                rbh[c] = *(const s16x8*)(Bh + g);
                rbl[c] = *(const s16x8*)(Bl + g);
            }
        }
        // fragments + MFMA (one 16x16x32 k-step per BK=32)
        s16x8 afh[4], afl[4], bfh[FN], bfl[FN];
#pragma unroll
        for (int i = 0; i < 4; ++i) {
            int slot = (quad*(BM+1) + wm + i*16 + l16) * 8;
            afh[i] = *(const s16x8*)&AhS[slot];
            afl[i] = *(const s16x8*)&AlS[slot];
        }
#pragma unroll
        for (int j = 0; j < FN; ++j) {
            int slot = (quad*(BN+1) + wn + j*16 + l16) * 8;
            bfh[j] = *(const s16x8*)&BhS[slot];
            bfl[j] = *(const s16x8*)&BlS[slot];
        }
#pragma unroll
        for (int i = 0; i < 4; ++i)
#pragma unroll
            for (int j = 0; j < FN; ++j) {
                acc[i][j] = __builtin_amdgcn_mfma_f32_16x16x32_bf16(afl[i], bfh[j], acc[i][j], 0, 0, 0);
                acc[i][j] = __builtin_amdgcn_mfma_f32_16x16x32_bf16(afh[i], bfl[j], acc[i][j], 0, 0, 0);
                acc[i][j] = __builtin_amdgcn_mfma_f32_16x16x32_bf16(afh[i], bfh[j], acc[i][j], 0, 0, 0);
            }
    }

    // epilogue: C/D layout col=lane&15, row=quad*4+reg
#pragma unroll
    for (int i = 0; i < 4; ++i)
#pragma unroll
        for (int j = 0; j < FN; ++j) {
            int col = n0 + wn + j*16 + l16;
#pragma unroll
            for (int r = 0; r < 4; ++r) {
                int rowc = m0 + wm + i*16 + quad*4 + r;
                C[(size_t)rowc * ldc + col] = acc[i][j][r];
            }
        }
}

// ---------------------------------------------------------------------------
// Sum the two K-split partials and emit split-bf16 pair (for next-layer GEMM).
__global__ __launch_bounds__(256) void combine2_kernel(
    const float* __restrict__ p0, const float* __restrict__ p1,
    u16* __restrict__ Hh, u16* __restrict__ Hl)
{
    int i = blockIdx.x * 256 + threadIdx.x;      // 4-elem chunk
    float4 a = ((const float4*)p0)[i];
    float4 b = ((const float4*)p1)[i];
    float v[4] = {a.x+b.x, a.y+b.y, a.z+b.z, a.w+b.w};
    u16x4v hv, lv;
#pragma unroll
    for (int r = 0; r < 4; ++r) {
        u16 hi, lo; split_bf16(v[r], hi, lo);
        hv[r] = hi; lv[r] = lo;
    }
    *(u16x4v*)(Hh + (size_t)i*4) = hv;
    *(u16x4v*)(Hl + (size_t)i*4) = lv;
}

// ---------------------------------------------------------------------------
// Depthwise causal conv (k=4) + bias + SiLU. Reads xc = xz[:, 0:1024].
__global__ __launch_bounds__(256) void conv_silu_kernel(
    const float* __restrict__ xz, const float* __restrict__ cw,
    const float* __restrict__ cb, float* __restrict__ u)
{
    int idx = blockIdx.x * 256 + threadIdx.x;   // MTOT*DINNER
    int m = idx >> 10;
    int d = idx & (DINNER - 1);
    int l = m & (L_ - 1);

    const float4 w = *(const float4*)&cw[d * 4];
    float acc = cb[d];
    if (l >= 3) acc += xz[(size_t)(m-3) * 2048 + d] * w.x;
    if (l >= 2) acc += xz[(size_t)(m-2) * 2048 + d] * w.y;
    if (l >= 1) acc += xz[(size_t)(m-1) * 2048 + d] * w.z;
    acc             += xz[(size_t)m     * 2048 + d] * w.w;
    u[idx] = acc / (1.f + __expf(-acc));   // silu
}

// ---------------------------------------------------------------------------
// x-proj partial GEMM: part[p][m][n] = sum_{k in split p} u[m,k]*W[n,k]
__global__ __launch_bounds__(256) void xp_kernel(
    const float* __restrict__ u, const float* __restrict__ W,
    float* __restrict__ part)
{
    __shared__ float As[16][68];
    __shared__ float Ws[64][65];
    const int p  = blockIdx.x;
    const int m0 = blockIdx.y * 16;
    const int t  = threadIdx.x;
    const int kb = p * 256;
    const int n  = t & 63;
    const int mi = t >> 6;
    float acc[4] = {0.f, 0.f, 0.f, 0.f};

    for (int kt = 0; kt < 256; kt += 64) {
        const int k0 = kb + kt;
        __syncthreads();
        {   // stage A tile 16x64
            int r = t >> 4, cc = t & 15;
            float4 v = *(const float4*)&u[(size_t)(m0 + r) * DINNER + k0 + cc*4];
            As[r][cc*4+0] = v.x; As[r][cc*4+1] = v.y; As[r][cc*4+2] = v.z; As[r][cc*4+3] = v.w;
        }
        {   // stage W tile 64x64
            int r = t >> 2, f = t & 3;
#pragma unroll
            for (int q = 0; q < 4; ++q) {
                float4 v = *(const float4*)&W[(size_t)r * DINNER + k0 + f*16 + q*4];
                Ws[r][f*16+q*4+0] = v.x; Ws[r][f*16+q*4+1] = v.y;
                Ws[r][f*16+q*4+2] = v.z; Ws[r][f*16+q*4+3] = v.w;
            }
        }
        __syncthreads();
#pragma unroll 8
        for (int kk = 0; kk < 64; ++kk) {
            float w = Ws[n][kk];
#pragma unroll
            for (int j = 0; j < 4; ++j) acc[j] += As[mi*4+j][kk] * w;
        }
    }
#pragma unroll
    for (int j = 0; j < 4; ++j)
        part[((size_t)p * MTOT + m0 + mi*4 + j) * 64 + n] = acc[j];
}

// Sum the 4 K-split partials -> xdbl.
__global__ __launch_bounds__(256) void xpsum_kernel(
    const float* __restrict__ part, float* __restrict__ xdbl)
{
    int i = blockIdx.x * 256 + threadIdx.x;          // MTOT*64/4 = 65536
    const size_t stride = (size_t)MTOT * 64 / 4;
    const float4* p = (const float4*)part;
    float4 a = p[i], b = p[i + stride], c = p[i + 2*stride], d = p[i + 3*stride];
    float4 o = make_float4(a.x+b.x+c.x+d.x, a.y+b.y+c.y+d.y,
                           a.z+b.z+c.z+d.z, a.w+b.w+c.w+d.w);
    ((float4*)xdbl)[i] = o;
}

// ---------------------------------------------------------------------------
// dt = softplus(dt_lr @ Wdt^T + b_dt); 8 rows of m per block.
__global__ __launch_bounds__(256) void dt_kernel(
    const float* __restrict__ xdbl, const float* __restrict__ Wdt,
    const float* __restrict__ bdt, float* __restrict__ dt)
{
    __shared__ float a[8][DTRANK];
    const int m0 = blockIdx.x * 8;
    const int t = threadIdx.x;
    if (t < 8 * DTRANK) a[t >> 5][t & 31] = xdbl[(size_t)(m0 + (t >> 5)) * 64 + (t & 31)];
    __syncthreads();
    for (int n = t; n < DINNER; n += 256) {
        const float* w = Wdt + (size_t)n * DTRANK;
        float bb = bdt[n];
        float acc[8];
#pragma unroll
        for (int r = 0; r < 8; ++r) acc[r] = bb;
#pragma unroll
        for (int k = 0; k < DTRANK; ++k) {
            float wk = w[k];
#pragma unroll
            for (int r = 0; r < 8; ++r) acc[r] += a[r][k] * wk;
        }
#pragma unroll
        for (int r = 0; r < 8; ++r) {
            float v = acc[r];
            float sp = (v > 20.f) ? v : log1pf(expf(v));
            dt[(size_t)(m0 + r) * DINNER + n] = sp;
        }
    }
}

// ---------------------------------------------------------------------------
// Chunked scan pass 1 — one lane per (b,c,d), 16 states in VGPRs.
__global__ __launch_bounds__(256) void scan1_kernel(
    const float* __restrict__ u, const float* xdbl,
    const float* __restrict__ dtp, const float* __restrict__ A_log,
    float* __restrict__ hfinal, float* dtsum_out)
{
    __shared__ float Bs[CLEN][16];
    const int blk  = blockIdx.x;              // b*128 + c*4 + dblk
    const int dblk = blk & 3;
    const int c    = (blk >> 2) & (CHUNKS - 1);
    const int b    = blk >> 7;
    const int d    = dblk * 256 + threadIdx.x;
    const int mbase = b * L_ + c * CLEN;

#pragma unroll
    for (int q = 0; q < 2; ++q) {
        int idx = q * 256 + threadIdx.x;
        int tt = idx >> 4, ss = idx & 15;
        Bs[tt][ss] = xdbl[(size_t)(mbase + tt) * 64 + 32 + ss];
    }
    float A[16];
    {
        float4 a4[4];
#pragma unroll
        for (int q = 0; q < 4; ++q) a4[q] = *(const float4*)&A_log[d * 16 + q * 4];
        const float* af = (const float*)a4;
#pragma unroll
        for (int s = 0; s < 16; ++s) A[s] = -__expf(af[s]);
    }
    __syncthreads();

    float h[16];
#pragma unroll
    for (int s = 0; s < 16; ++s) h[s] = 0.f;
    float dts = 0.f;

    for (int t0 = 0; t0 < CLEN; t0 += 8) {
        float dt8[8], u8[8];
#pragma unroll
        for (int j = 0; j < 8; ++j) {
            int m = mbase + t0 + j;
            dt8[j] = dtp[(size_t)m * DINNER + d];
            u8[j]  = u [(size_t)m * DINNER + d];
        }
#pragma unroll
        for (int j = 0; j < 8; ++j) {
            float dtv = dt8[j], dtu = dtv * u8[j];
            dts += dtv;
            float Bt[16];
#pragma unroll
            for (int q = 0; q < 4; ++q)
                *(float4*)&Bt[q*4] = *(const float4*)&Bs[t0 + j][q*4];
#pragma unroll
            for (int s = 0; s < 16; ++s) {
                float dA = __expf(dtv * A[s]);
                h[s] = dA * h[s] + dtu * Bt[s];
            }
        }
    }
    size_t base = ((size_t)(b * CHUNKS + c) * DINNER + d) * 16;
#pragma unroll
    for (int q = 0; q < 4; ++q)
        *(float4*)&hfinal[base + q*4] = make_float4(h[q*4], h[q*4+1], h[q*4+2], h[q*4+3]);
    int i = (b * CHUNKS + c) * DINNER + d;
    dtsum_out[(i >> 5) * 64 + (i & 31)] = dts;   // dead dt_lr cols of xdbl
}

// Pass 2: sequential chunk fix-up.
__global__ __launch_bounds__(256) void scan2_kernel(
    float* __restrict__ hfinal, const float* __restrict__ dtsum,
    const float* __restrict__ A_log)
{
    int t = blockIdx.x * 256 + threadIdx.x;   // 65536 = B_*DINNER*DSTATE
    int s = t & 15, d = (t >> 4) & (DINNER - 1), b = t >> 14;
    float As = -__expf(A_log[d * DSTATE + s]);
    float h = 0.f;
    for (int c0 = 0; c0 < CHUNKS; c0 += 8) {
        float hf8[8], dts8[8];
#pragma unroll
        for (int j = 0; j < 8; ++j) {
            int c = c0 + j;
            int i = (b * CHUNKS + c) * DINNER + d;
            dts8[j] = dtsum[(i >> 5) * 64 + (i & 31)];
            hf8[j]  = hfinal[((size_t)i) * 16 + s];
        }
#pragma unroll
        for (int j = 0; j < 8; ++j) {
            int c = c0 + j;
            size_t idx = ((size_t)((b * CHUNKS + c) * DINNER + d)) * 16 + s;
            hfinal[idx] = h;
            h = __expf(As * dts8[j]) * h + hf8[j];
        }
    }
}

// Pass 3: seeded local scan; y = (C.h + u*D)*silu(z), written as bf16 pair.
__global__ __launch_bounds__(256) void scan3_kernel(
    const float* __restrict__ xz, const float* __restrict__ u,
    const float* xdbl, const float* __restrict__ dtp,
    const float* __restrict__ A_log, const float* __restrict__ Dp,
    const float* __restrict__ hstart, u16* __restrict__ yh, u16* __restrict__ yl)
{
    __shared__ float Bs[CLEN][16];
    __shared__ float Cs[CLEN][16];
    const int blk  = blockIdx.x;
    const int dblk = blk & 3;
    const int c    = (blk >> 2) & (CHUNKS - 1);
    const int b    = blk >> 7;
    const int d    = dblk * 256 + threadIdx.x;
    const int mbase = b * L_ + c * CLEN;

#pragma unroll
    for (int q = 0; q < 2; ++q) {
        int idx = q * 256 + threadIdx.x;
        int tt = idx >> 4, ss = idx & 15;
        Bs[tt][ss] = xdbl[(size_t)(mbase + tt) * 64 + 32 + ss];
        Cs[tt][ss] = xdbl[(size_t)(mbase + tt) * 64 + 48 + ss];
    }
    float A[16];
    {
        float4 a4[4];
#pragma unroll
        for (int q = 0; q < 4; ++q) a4[q] = *(const float4*)&A_log[d * 16 + q * 4];
        const float* af = (const float*)a4;
#pragma unroll
        for (int s = 0; s < 16; ++s) A[s] = -__expf(af[s]);
    }
    const float Dval = Dp[d];

    float h[16];
    {
        size_t base = ((size_t)(b * CHUNKS + c) * DINNER + d) * 16;
#pragma unroll
        for (int q = 0; q < 4; ++q) {
            float4 v = *(const float4*)&hstart[base + q*4];
            h[q*4] = v.x; h[q*4+1] = v.y; h[q*4+2] = v.z; h[q*4+3] = v.w;
        }
    }
    __syncthreads();

    for (int t0 = 0; t0 < CLEN; t0 += 8) {
        float dt8[8], u8[8], z8[8];
#pragma unroll
        for (int j = 0; j < 8; ++j) {
            int m = mbase + t0 + j;
            dt8[j] = dtp[(size_t)m * DINNER + d];
            u8[j]  = u [(size_t)m * DINNER + d];
            z8[j]  = xz[(size_t)m * 2048 + DINNER + d];
        }
#pragma unroll
        for (int j = 0; j < 8; ++j) {
            float dtv = dt8[j], dtu = dtv * u8[j];
            float Bt[16], Ct[16];
#pragma unroll
            for (int q = 0; q < 4; ++q) {
                *(float4*)&Bt[q*4] = *(const float4*)&Bs[t0 + j][q*4];
                *(float4*)&Ct[q*4] = *(const float4*)&Cs[t0 + j][q*4];
            }
            float yv = 0.f;
#pragma unroll
            for (int s = 0; s < 16; ++s) {
                float dA = __expf(dtv * A[s]);
                h[s] = dA * h[s] + dtu * Bt[s];
                yv += h[s] * Ct[s];
            }
            float zv = z8[j];
            float sz = zv / (1.f + __expf(-zv));
            float yval = (yv + u8[j] * Dval) * sz;
            u16 hi, lo; split_bf16(yval, hi, lo);
            int m = mbase + t0 + j;
            yh[(size_t)m * DINNER + d] = hi;
            yl[(size_t)m * DINNER + d] = lo;
        }
    }
}

// ---------------------------------------------------------------------------
// Final LayerNorm over DMODEL=512, reading the bf16-pair h.
__global__ __launch_bounds__(256) void ln_kernel(
    const u16* __restrict__ hh, const u16* __restrict__ hl,
    const float* __restrict__ g, const float* __restrict__ bta,
    float* __restrict__ out)
{
    int m = blockIdx.x;
    size_t base = (size_t)m * DMODEL;
    int t = threadIdx.x;
    float v0 = join_bf16(hh[base + t],       hl[base + t]);
    float v1 = join_bf16(hh[base + t + 256], hl[base + t + 256]);
    float sum = v0 + v1, sq = v0*v0 + v1*v1;
#pragma unroll
    for (int off = 32; off; off >>= 1) {
        sum += __shfl_down(sum, off);
        sq  += __shfl_down(sq,  off);
    }
    __shared__ float ls[4], lq[4];
    int w = t >> 6;
    if ((t & 63) == 0) { ls[w] = sum; lq[w] = sq; }
    __syncthreads();
    sum = ls[0] + ls[1] + ls[2] + ls[3];
    sq  = lq[0] + lq[1] + lq[2] + lq[3];
    float mu  = sum * (1.f / DMODEL);
    float var = sq * (1.f / DMODEL) - mu * mu;
    float rs  = rsqrtf(var + 1e-5f);
    out[base + t]       = (v0 - mu) * rs * g[t]       + bta[t];
    out[base + t + 256] = (v1 - mu) * rs * g[t + 256] + bta[t + 256];
}

// ---------------------------------------------------------------------------
extern "C" void kernel_launch(void* const* d_in, const int* in_sizes, int n_in,
                              void* d_out, int out_size, void* d_ws, size_t ws_size,
                              hipStream_t stream)
{
    const float* x      = (const float*)d_in[0];
    const float* in_w   = (const float*)d_in[1];
    const float* in_b   = (const float*)d_in[2];
    const float* W_xz   = (const float*)d_in[3];
    const float* conv_w = (const float*)d_in[4];
    const float* conv_b = (const float*)d_in[5];
    const float* W_xp   = (const float*)d_in[6];
    const float* W_dt   = (const float*)d_in[7];
    const float* b_dt   = (const float*)d_in[8];
    const float* A_log  = (const float*)d_in[9];
    const float* D_par  = (const float*)d_in[10];
    const float* W_out  = (const float*)d_in[11];
    const float* ln_g   = (const float*)d_in[12];
    const float* ln_b   = (const float*)d_in[13];
    float* out = (float*)d_out;

    // Workspace layout (floats), total 22.26 M floats = 89.0 MB (< proven 93.3):
    float* ws   = (float*)d_ws;
    float* hreg = ws;                    // 2 M  : h bf16-pair (hh|hl) + hfinal alias
    float* xz   = hreg + 2097152;        // 8 M  : xz fp32
    float* u    = xz   + 8388608;        // 4 M  : u fp32; wxz/wout pairs alias (dead windows)
    float* xdbl = u    + 4194304;        // 262144
    float* dtb  = xdbl + 262144;         // 4 M  : xpart -> dt -> out-GEMM partials
    float* yreg = dtb  + 4194304;        // 4 M  : y bf16-pair (yh|yl)

    u16* hh = (u16*)hreg;
    u16* hl = (u16*)(hreg + 1048576);
    float* hfinal = hreg;                // alive only scan1..scan3 (hh/hl dead then)
    float* xpart  = dtb;                 // dead after xpsum
    float* dt     = dtb;                 // written after xpart dies, dead after scan3
    float* part0  = dtb;                 // out-GEMM split-K partials (after scan3)
    float* part1  = dtb + 2097152;
    u16* yh = (u16*)yreg;
    u16* yl = (u16*)(yreg + 2097152);
    u16* wxzh  = (u16*)u;                // Wxz pair: u dead before conv_silu
    u16* wxzl  = (u16*)(u + 524288);
    u16* wouth = (u16*)u;                // Wout pair: u dead after scan3
    u16* woutl = (u16*)(u + 262144);

    in_proj_kernel<<<MTOT*DMODEL/256, 256, 0, stream>>>(x, in_w, in_b, hh, hl);

    for (int layer = 0; layer < DEPTH_; ++layer) {
        const float* Wxz  = W_xz   + (size_t)layer * 2048 * DMODEL;
        const float* cw   = conv_w + (size_t)layer * DINNER * DCONV;
        const float* cb   = conv_b + (size_t)layer * DINNER;
        const float* Wxp  = W_xp   + (size_t)layer * 64 * DINNER;
        const float* Wdt  = W_dt   + (size_t)layer * DINNER * DTRANK;
        const float* bdt  = b_dt   + (size_t)layer * DINNER;
        const float* Alog = A_log  + (size_t)layer * DINNER * DSTATE;
        const float* Dp   = D_par  + (size_t)layer * DINNER;
        const float* Wout = W_out  + (size_t)layer * DMODEL * DINNER;

        // Wxz -> bf16 pair (into dead u region), then xz = h @ Wxz^T (fp32 out)
        wconv_kernel<<<(2048*DMODEL/8)/256, 256, 0, stream>>>(Wxz, wxzh, wxzl);
        gemm_pair<128><<<dim3(2048/128, MTOT/128, 1), 256, 0, stream>>>(
            hh, hl, DMODEL, wxzh, wxzl, DMODEL, xz, 2048, DMODEL, 0);
        // u = silu(conv(xc) + cb)  (overwrites wxz pair — dead)
        conv_silu_kernel<<<MTOT*DINNER/256, 256, 0, stream>>>(xz, cw, cb, u);
        // xdbl = u @ Wxp^T (K-split x4 + reduce), partials in dtb
        xp_kernel<<<dim3(4, MTOT/16), 256, 0, stream>>>(u, Wxp, xpart);
        xpsum_kernel<<<(MTOT*64/4)/256, 256, 0, stream>>>(xpart, xdbl);
        // dt = softplus(dt_lr @ Wdt^T + b_dt)
        dt_kernel<<<MTOT/8, 256, 0, stream>>>(xdbl, Wdt, bdt, dt);
        // chunked selective scan
        scan1_kernel<<<B_*CHUNKS*(DINNER/256), 256, 0, stream>>>(u, xdbl, dt, Alog, hfinal, xdbl);
        scan2_kernel<<<(B_*DINNER*DSTATE)/256, 256, 0, stream>>>(hfinal, xdbl, Alog);
        scan3_kernel<<<B_*CHUNKS*(DINNER/256), 256, 0, stream>>>(xz, u, xdbl, dt, Alog, Dp, hfinal, yh, yl);
        // Wout -> bf16 pair (u dead), then h = y @ Wout^T, split-K x2 -> combine
        wconv_kernel<<<(DMODEL*DINNER/8)/256, 256, 0, stream>>>(Wout, wouth, woutl);
        gemm_pair<64><<<dim3(DMODEL/64, MTOT/128, 2), 256, 0, stream>>>(
            yh, yl, DINNER, wouth, woutl, DINNER, part0, DMODEL, DINNER/2,
            (size_t)MTOT * DMODEL);
        combine2_kernel<<<(MTOT*DMODEL/4)/256, 256, 0, stream>>>(part0, part1, hh, hl);
    }

    ln_kernel<<<MTOT, 256, 0, stream>>>(hh, hl, ln_g, ln_b, out);
}

// Round 8
// 716.980 us; speedup vs baseline: 5.1848x; 1.1602x over previous
//
#include <hip/hip_runtime.h>
#include <math.h>

// Problem constants (match reference)
#define B_      4
#define L_      1024
#define D_INNC  8      // D_IN
#define DMODEL  512
#define DEPTH_  4
#define DINNER  1024
#define DSTATE  16
#define DCONV   4
#define DTRANK  32
#define MTOT    (B_*L_)   // 4096
#define CHUNKS  32
#define CLEN    32        // L_/CHUNKS

typedef float f32x4 __attribute__((ext_vector_type(4)));
typedef short s16x8 __attribute__((ext_vector_type(8)));
typedef unsigned short u16;
typedef unsigned short u16x4v __attribute__((ext_vector_type(4)));

// fp32 -> bf16 round-to-nearest-even
__device__ __forceinline__ u16 f2bf(float v) {
    unsigned b = __float_as_uint(v);
    return (u16)((b + 0x7FFF + ((b >> 16) & 1)) >> 16);
}
__device__ __forceinline__ float bf2f(u16 h) {
    return __uint_as_float((unsigned)h << 16);
}

// ---------------------------------------------------------------------------
// h = x @ in_w^T + in_b  -> bf16 (4096 x 512, K=8)
__global__ __launch_bounds__(256) void in_proj_kernel(
    const float* __restrict__ x, const float* __restrict__ w,
    const float* __restrict__ bias, u16* __restrict__ hb)
{
    int idx = blockIdx.x * 256 + threadIdx.x;
    int m = idx / DMODEL, d = idx % DMODEL;
    const float* xr = x + m * D_INNC;
    const float* wr = w + d * D_INNC;
    float acc = bias[d];
#pragma unroll
    for (int k = 0; k < D_INNC; ++k) acc += xr[k] * wr[k];
    hb[idx] = f2bf(acc);
}

// ---------------------------------------------------------------------------
// fp32 -> bf16 array convert, 8 elems/thread.
__global__ __launch_bounds__(256) void wconv_kernel(
    const float* __restrict__ W, u16* __restrict__ Wb)
{
    int i = blockIdx.x * 256 + threadIdx.x;
    const float* src = W + (size_t)i * 8;
    float4 f0 = *(const float4*)src;
    float4 f1 = *(const float4*)(src + 4);
    float f[8] = {f0.x,f0.y,f0.z,f0.w,f1.x,f1.y,f1.z,f1.w};
    s16x8 hv;
#pragma unroll
    for (int e = 0; e < 8; ++e) hv[e] = (short)f2bf(f[e]);
    *(s16x8*)(Wb + (size_t)i * 8) = hv;
}

// ---------------------------------------------------------------------------
// bf16 MFMA NT GEMM: C[m,n] = sum_k A[m,k]*B[n,k].
// BM=128, BK=32, 256 thr (4 waves 2x2), wave tile 64 x (BN/2).
// MODE 0: fp32 out to C0 (+ blockIdx.z*pstride), leading dim ldc, K-slice kLen.
// MODE 1: xz epilogue — col<1024: bf16 -> xcb; col>=1024: silu -> bf16 szb.
template<int BN, int MODE>
__global__ __launch_bounds__(256, 2) void gemm_bf16(
    const u16* __restrict__ A, int lda,
    const u16* __restrict__ B, int ldb,
    void* __restrict__ C0, void* __restrict__ C1,
    int ldc, int kLen, size_t pstride)
{
    constexpr int BM  = 128;
    constexpr int FN  = BN / 32;            // n-fragments per wave
    constexpr int ACH = 2;                  // A 8-elem chunks per thread
    constexpr int BCH = BN / 64;            // B chunks per thread
    __shared__ __align__(16) u16 As[4*(BM+1)*8];
    __shared__ __align__(16) u16 Bs[4*(BN+1)*8];

    const int t    = threadIdx.x;
    const int lane = t & 63;
    const int w    = t >> 6;
    const int wm   = (w >> 1) * 64;
    const int wn   = (w & 1) * (BN / 2);
    const int quad = lane >> 4;
    const int l16  = lane & 15;
    const int m0   = blockIdx.y * BM;
    const int n0   = blockIdx.x * BN;
    const int kstart = blockIdx.z * kLen;
    const int kend   = kstart + kLen;

    f32x4 acc[4][FN];
#pragma unroll
    for (int i = 0; i < 4; ++i)
#pragma unroll
        for (int j = 0; j < FN; ++j) acc[i][j] = (f32x4){0.f,0.f,0.f,0.f};

    s16x8 ra[ACH], rb[BCH];
#pragma unroll
    for (int c = 0; c < ACH; ++c) {
        int id = c*256 + t, row = id >> 2, kb = id & 3;
        ra[c] = *(const s16x8*)(A + (size_t)(m0 + row) * lda + kstart + kb*8);
    }
#pragma unroll
    for (int c = 0; c < BCH; ++c) {
        int id = c*256 + t, row = id >> 2, kb = id & 3;
        rb[c] = *(const s16x8*)(B + (size_t)(n0 + row) * ldb + kstart + kb*8);
    }

    for (int kk = kstart; kk < kend; kk += 32) {
        __syncthreads();
#pragma unroll
        for (int c = 0; c < ACH; ++c) {
            int id = c*256 + t, row = id >> 2, kb = id & 3;
            *(s16x8*)&As[(kb*(BM+1) + row) * 8] = ra[c];
        }
#pragma unroll
        for (int c = 0; c < BCH; ++c) {
            int id = c*256 + t, row = id >> 2, kb = id & 3;
            *(s16x8*)&Bs[(kb*(BN+1) + row) * 8] = rb[c];
        }
        __syncthreads();
        int kn = kk + 32;
        if (kn < kend) {   // prefetch next K-slice, overlaps MFMA below
#pragma unroll
            for (int c = 0; c < ACH; ++c) {
                int id = c*256 + t, row = id >> 2, kb = id & 3;
                ra[c] = *(const s16x8*)(A + (size_t)(m0 + row) * lda + kn + kb*8);
            }
#pragma unroll
            for (int c = 0; c < BCH; ++c) {
                int id = c*256 + t, row = id >> 2, kb = id & 3;
                rb[c] = *(const s16x8*)(B + (size_t)(n0 + row) * ldb + kn + kb*8);
            }
        }
        s16x8 afr[4], bfr[FN];
#pragma unroll
        for (int i = 0; i < 4; ++i)
            afr[i] = *(const s16x8*)&As[(quad*(BM+1) + wm + i*16 + l16) * 8];
#pragma unroll
        for (int j = 0; j < FN; ++j)
            bfr[j] = *(const s16x8*)&Bs[(quad*(BN+1) + wn + j*16 + l16) * 8];
#pragma unroll
        for (int i = 0; i < 4; ++i)
#pragma unroll
            for (int j = 0; j < FN; ++j)
                acc[i][j] = __builtin_amdgcn_mfma_f32_16x16x32_bf16(afr[i], bfr[j], acc[i][j], 0, 0, 0);
    }

    // epilogue: C/D layout col=lane&15, row=quad*4+reg
    if (MODE == 0) {
        float* C = (float*)C0 + (size_t)blockIdx.z * pstride;
#pragma unroll
        for (int i = 0; i < 4; ++i)
#pragma unroll
            for (int j = 0; j < FN; ++j) {
                int col = n0 + wn + j*16 + l16;
#pragma unroll
                for (int r = 0; r < 4; ++r) {
                    int row = m0 + wm + i*16 + quad*4 + r;
                    C[(size_t)row * ldc + col] = acc[i][j][r];
                }
            }
    } else {
        u16* xcb = (u16*)C0;
        u16* szb = (u16*)C1;
#pragma unroll
        for (int i = 0; i < 4; ++i)
#pragma unroll
            for (int j = 0; j < FN; ++j) {
                int col = n0 + wn + j*16 + l16;
                bool isz = col >= DINNER;
                int cc = col & (DINNER - 1);
                u16* dst = isz ? szb : xcb;
#pragma unroll
                for (int r = 0; r < 4; ++r) {
                    int row = m0 + wm + i*16 + quad*4 + r;
                    float v = acc[i][j][r];
                    if (isz) v = v / (1.f + __expf(-v));   // silu(z)
                    dst[(size_t)row * DINNER + cc] = f2bf(v);
                }
            }
    }
}

// ---------------------------------------------------------------------------
// Depthwise causal conv (k=4) + bias + SiLU; bf16 in/out. 2 d-channels/thread.
__global__ __launch_bounds__(256) void conv_silu_kernel(
    const u16* __restrict__ xcb, const float* __restrict__ cw,
    const float* __restrict__ cb, u16* __restrict__ ub)
{
    int idx = (blockIdx.x * 256 + threadIdx.x) * 2;   // MTOT*DINNER, even
    int m = idx >> 10;
    int d = idx & (DINNER - 1);
    int l = m & (L_ - 1);

    const float4 w0 = *(const float4*)&cw[d * 4];
    const float4 w1 = *(const float4*)&cw[(d + 1) * 4];
    float a0 = cb[d], a1 = cb[d + 1];
#pragma unroll
    for (int k = 0; k < 4; ++k) {
        int lag = 3 - k;
        if (l >= lag) {
            unsigned v = *(const unsigned*)&xcb[(size_t)(m - lag) * DINNER + d];
            float x0 = bf2f((u16)(v & 0xffff));
            float x1 = bf2f((u16)(v >> 16));
            float wk0 = (&w0.x)[k], wk1 = (&w1.x)[k];
            a0 += x0 * wk0; a1 += x1 * wk1;
        }
    }
    a0 = a0 / (1.f + __expf(-a0));
    a1 = a1 / (1.f + __expf(-a1));
    unsigned pack = (unsigned)f2bf(a0) | ((unsigned)f2bf(a1) << 16);
    *(unsigned*)&ub[idx] = pack;
}

// ---------------------------------------------------------------------------
// x-proj partial GEMM: part[p][m][n] = sum_{k in split p} u[m,k]*W[n,k]
// u is bf16 (converted to fp32 during LDS staging). BM=16, N=64, K-split 4x256.
__global__ __launch_bounds__(256) void xp_kernel(
    const u16* __restrict__ ub, const float* __restrict__ W,
    float* __restrict__ part)
{
    __shared__ float As[16][68];
    __shared__ float Ws[64][65];
    const int p  = blockIdx.x;
    const int m0 = blockIdx.y * 16;
    const int t  = threadIdx.x;
    const int kb = p * 256;
    const int n  = t & 63;
    const int mi = t >> 6;
    float acc[4] = {0.f, 0.f, 0.f, 0.f};

    for (int kt = 0; kt < 256; kt += 64) {
        const int k0 = kb + kt;
        __syncthreads();
        {   // stage A tile 16x64 (bf16 -> fp32)
            int r = t >> 4, cc = t & 15;
            u16x4v v = *(const u16x4v*)&ub[(size_t)(m0 + r) * DINNER + k0 + cc*4];
#pragma unroll
            for (int e = 0; e < 4; ++e) As[r][cc*4+e] = bf2f(v[e]);
        }
        {   // stage W tile 64x64
            int r = t >> 2, f = t & 3;
#pragma unroll
            for (int q = 0; q < 4; ++q) {
                float4 v = *(const float4*)&W[(size_t)r * DINNER + k0 + f*16 + q*4];
                Ws[r][f*16+q*4+0] = v.x; Ws[r][f*16+q*4+1] = v.y;
                Ws[r][f*16+q*4+2] = v.z; Ws[r][f*16+q*4+3] = v.w;
            }
        }
        __syncthreads();
#pragma unroll 8
        for (int kk = 0; kk < 64; ++kk) {
            float w = Ws[n][kk];
#pragma unroll
            for (int j = 0; j < 4; ++j) acc[j] += As[mi*4+j][kk] * w;
        }
    }
#pragma unroll
    for (int j = 0; j < 4; ++j)
        part[((size_t)p * MTOT + m0 + mi*4 + j) * 64 + n] = acc[j];
}

// ---------------------------------------------------------------------------
// Fused: sum 4 K-split partials (-> B/C cols of xdbl) + dt GEMM + softplus.
// 8 m-rows per block.
__global__ __launch_bounds__(256) void dtsum_kernel(
    const float* __restrict__ part, const float* __restrict__ Wdt,
    const float* __restrict__ bdt, float* __restrict__ xdbl,
    u16* __restrict__ dtb)
{
    __shared__ float a[8][64];
    const int m0 = blockIdx.x * 8;
    const int t = threadIdx.x;
#pragma unroll
    for (int e = 0; e < 2; ++e) {
        int id = e * 256 + t;
        int r = id >> 6, c = id & 63;
        float s = 0.f;
#pragma unroll
        for (int p = 0; p < 4; ++p)
            s += part[((size_t)p * MTOT + m0 + r) * 64 + c];
        a[r][c] = s;
        if (c >= 32) xdbl[(size_t)(m0 + r) * 64 + c] = s;   // B,C for scans
    }
    __syncthreads();
    for (int n = t; n < DINNER; n += 256) {
        const float* w = Wdt + (size_t)n * DTRANK;
        float bb = bdt[n];
        float acc[8];
#pragma unroll
        for (int r = 0; r < 8; ++r) acc[r] = bb;
#pragma unroll
        for (int k = 0; k < DTRANK; ++k) {
            float wk = w[k];
#pragma unroll
            for (int r = 0; r < 8; ++r) acc[r] += a[r][k] * wk;
        }
#pragma unroll
        for (int r = 0; r < 8; ++r) {
            float v = acc[r];
            float sp = (v > 20.f) ? v : log1pf(expf(v));
            dtb[(size_t)(m0 + r) * DINNER + n] = f2bf(sp);
        }
    }
}

// ---------------------------------------------------------------------------
// Chunked scan pass 1 — one lane per (b,c,d), 16 states in VGPRs.
__global__ __launch_bounds__(256) void scan1_kernel(
    const u16* __restrict__ ub, const float* xdbl,
    const u16* __restrict__ dtb, const float* __restrict__ A_log,
    float* __restrict__ hfinal, float* dtsum_out)
{
    __shared__ float Bs[CLEN][16];
    const int blk  = blockIdx.x;              // b*128 + c*4 + dblk
    const int dblk = blk & 3;
    const int c    = (blk >> 2) & (CHUNKS - 1);
    const int b    = blk >> 7;
    const int d    = dblk * 256 + threadIdx.x;
    const int mbase = b * L_ + c * CLEN;

#pragma unroll
    for (int q = 0; q < 2; ++q) {
        int idx = q * 256 + threadIdx.x;
        int tt = idx >> 4, ss = idx & 15;
        Bs[tt][ss] = xdbl[(size_t)(mbase + tt) * 64 + 32 + ss];
    }
    float A[16];
    {
        float4 a4[4];
#pragma unroll
        for (int q = 0; q < 4; ++q) a4[q] = *(const float4*)&A_log[d * 16 + q * 4];
        const float* af = (const float*)a4;
#pragma unroll
        for (int s = 0; s < 16; ++s) A[s] = -__expf(af[s]);
    }
    __syncthreads();

    float h[16];
#pragma unroll
    for (int s = 0; s < 16; ++s) h[s] = 0.f;
    float dts = 0.f;

    for (int t0 = 0; t0 < CLEN; t0 += 8) {
        float dt8[8], u8[8];
#pragma unroll
        for (int j = 0; j < 8; ++j) {
            int m = mbase + t0 + j;
            dt8[j] = bf2f(dtb[(size_t)m * DINNER + d]);
            u8[j]  = bf2f(ub [(size_t)m * DINNER + d]);
        }
#pragma unroll
        for (int j = 0; j < 8; ++j) {
            float dtv = dt8[j], dtu = dtv * u8[j];
            dts += dtv;
            float Bt[16];
#pragma unroll
            for (int q = 0; q < 4; ++q)
                *(float4*)&Bt[q*4] = *(const float4*)&Bs[t0 + j][q*4];
#pragma unroll
            for (int s = 0; s < 16; ++s) {
                float dA = __expf(dtv * A[s]);
                h[s] = dA * h[s] + dtu * Bt[s];
            }
        }
    }
    size_t base = ((size_t)(b * CHUNKS + c) * DINNER + d) * 16;
#pragma unroll
    for (int q = 0; q < 4; ++q)
        *(float4*)&hfinal[base + q*4] = make_float4(h[q*4], h[q*4+1], h[q*4+2], h[q*4+3]);
    int i = (b * CHUNKS + c) * DINNER + d;
    dtsum_out[(i >> 5) * 64 + (i & 31)] = dts;   // dead dt_lr cols of xdbl
}

// Pass 2: sequential chunk fix-up: hfinal[c] <- true start state.
__global__ __launch_bounds__(256) void scan2_kernel(
    float* __restrict__ hfinal, const float* __restrict__ dtsum,
    const float* __restrict__ A_log)
{
    int t = blockIdx.x * 256 + threadIdx.x;   // 65536 = B_*DINNER*DSTATE
    int s = t & 15, d = (t >> 4) & (DINNER - 1), b = t >> 14;
    float As = -__expf(A_log[d * DSTATE + s]);
    float h = 0.f;
    for (int c0 = 0; c0 < CHUNKS; c0 += 8) {
        float hf8[8], dts8[8];
#pragma unroll
        for (int j = 0; j < 8; ++j) {
            int c = c0 + j;
            int i = (b * CHUNKS + c) * DINNER + d;
            dts8[j] = dtsum[(i >> 5) * 64 + (i & 31)];
            hf8[j]  = hfinal[((size_t)i) * 16 + s];
        }
#pragma unroll
        for (int j = 0; j < 8; ++j) {
            int c = c0 + j;
            size_t idx = ((size_t)((b * CHUNKS + c) * DINNER + d)) * 16 + s;
            hfinal[idx] = h;
            h = __expf(As * dts8[j]) * h + hf8[j];
        }
    }
}

// Pass 3: seeded local scan; y = (C.h + u*D)*sz, written bf16.
__global__ __launch_bounds__(256) void scan3_kernel(
    const u16* __restrict__ szb, const u16* __restrict__ ub,
    const float* xdbl, const u16* __restrict__ dtb,
    const float* __restrict__ A_log, const float* __restrict__ Dp,
    const float* __restrict__ hstart, u16* __restrict__ yb)
{
    __shared__ float Bs[CLEN][16];
    __shared__ float Cs[CLEN][16];
    const int blk  = blockIdx.x;
    const int dblk = blk & 3;
    const int c    = (blk >> 2) & (CHUNKS - 1);
    const int b    = blk >> 7;
    const int d    = dblk * 256 + threadIdx.x;
    const int mbase = b * L_ + c * CLEN;

#pragma unroll
    for (int q = 0; q < 2; ++q) {
        int idx = q * 256 + threadIdx.x;
        int tt = idx >> 4, ss = idx & 15;
        Bs[tt][ss] = xdbl[(size_t)(mbase + tt) * 64 + 32 + ss];
        Cs[tt][ss] = xdbl[(size_t)(mbase + tt) * 64 + 48 + ss];
    }
    float A[16];
    {
        float4 a4[4];
#pragma unroll
        for (int q = 0; q < 4; ++q) a4[q] = *(const float4*)&A_log[d * 16 + q * 4];
        const float* af = (const float*)a4;
#pragma unroll
        for (int s = 0; s < 16; ++s) A[s] = -__expf(af[s]);
    }
    const float Dval = Dp[d];

    float h[16];
    {
        size_t base = ((size_t)(b * CHUNKS + c) * DINNER + d) * 16;
#pragma unroll
        for (int q = 0; q < 4; ++q) {
            float4 v = *(const float4*)&hstart[base + q*4];
            h[q*4] = v.x; h[q*4+1] = v.y; h[q*4+2] = v.z; h[q*4+3] = v.w;
        }
    }
    __syncthreads();

    for (int t0 = 0; t0 < CLEN; t0 += 8) {
        float dt8[8], u8[8], sz8[8];
#pragma unroll
        for (int j = 0; j < 8; ++j) {
            int m = mbase + t0 + j;
            dt8[j] = bf2f(dtb[(size_t)m * DINNER + d]);
            u8[j]  = bf2f(ub [(size_t)m * DINNER + d]);
            sz8[j] = bf2f(szb[(size_t)m * DINNER + d]);
        }
#pragma unroll
        for (int j = 0; j < 8; ++j) {
            float dtv = dt8[j], dtu = dtv * u8[j];
            float Bt[16], Ct[16];
#pragma unroll
            for (int q = 0; q < 4; ++q) {
                *(float4*)&Bt[q*4] = *(const float4*)&Bs[t0 + j][q*4];
                *(float4*)&Ct[q*4] = *(const float4*)&Cs[t0 + j][q*4];
            }
            float yv = 0.f;
#pragma unroll
            for (int s = 0; s < 16; ++s) {
                float dA = __expf(dtv * A[s]);
                h[s] = dA * h[s] + dtu * Bt[s];
                yv += h[s] * Ct[s];
            }
            int m = mbase + t0 + j;
            yb[(size_t)m * DINNER + d] = f2bf((yv + u8[j] * Dval) * sz8[j]);
        }
    }
}

// ---------------------------------------------------------------------------
// Sum 2 K-split partials -> bf16 h.
__global__ __launch_bounds__(256) void combine2_kernel(
    const float* __restrict__ p0, const float* __restrict__ p1,
    u16* __restrict__ hb)
{
    int i = blockIdx.x * 256 + threadIdx.x;      // 4-elem chunk
    float4 a = ((const float4*)p0)[i];
    float4 b = ((const float4*)p1)[i];
    float v[4] = {a.x+b.x, a.y+b.y, a.z+b.z, a.w+b.w};
    u16x4v hv;
#pragma unroll
    for (int r = 0; r < 4; ++r) hv[r] = f2bf(v[r]);
    *(u16x4v*)(hb + (size_t)i*4) = hv;
}

// ---------------------------------------------------------------------------
// Final LayerNorm over DMODEL=512, reading bf16 h.
__global__ __launch_bounds__(256) void ln_kernel(
    const u16* __restrict__ hb, const float* __restrict__ g,
    const float* __restrict__ bta, float* __restrict__ out)
{
    int m = blockIdx.x;
    size_t base = (size_t)m * DMODEL;
    int t = threadIdx.x;
    float v0 = bf2f(hb[base + t]);
    float v1 = bf2f(hb[base + t + 256]);
    float sum = v0 + v1, sq = v0*v0 + v1*v1;
#pragma unroll
    for (int off = 32; off; off >>= 1) {
        sum += __shfl_down(sum, off);
        sq  += __shfl_down(sq,  off);
    }
    __shared__ float ls[4], lq[4];
    int w = t >> 6;
    if ((t & 63) == 0) { ls[w] = sum; lq[w] = sq; }
    __syncthreads();
    sum = ls[0] + ls[1] + ls[2] + ls[3];
    sq  = lq[0] + lq[1] + lq[2] + lq[3];
    float mu  = sum * (1.f / DMODEL);
    float var = sq * (1.f / DMODEL) - mu * mu;
    float rs  = rsqrtf(var + 1e-5f);
    out[base + t]       = (v0 - mu) * rs * g[t]       + bta[t];
    out[base + t + 256] = (v1 - mu) * rs * g[t + 256] + bta[t + 256];
}

// ---------------------------------------------------------------------------
extern "C" void kernel_launch(void* const* d_in, const int* in_sizes, int n_in,
                              void* d_out, int out_size, void* d_ws, size_t ws_size,
                              hipStream_t stream)
{
    const float* x      = (const float*)d_in[0];
    const float* in_w   = (const float*)d_in[1];
    const float* in_b   = (const float*)d_in[2];
    const float* W_xz   = (const float*)d_in[3];
    const float* conv_w = (const float*)d_in[4];
    const float* conv_b = (const float*)d_in[5];
    const float* W_xp   = (const float*)d_in[6];
    const float* W_dt   = (const float*)d_in[7];
    const float* b_dt   = (const float*)d_in[8];
    const float* A_log  = (const float*)d_in[9];
    const float* D_par  = (const float*)d_in[10];
    const float* W_out  = (const float*)d_in[11];
    const float* ln_g   = (const float*)d_in[12];
    const float* ln_b   = (const float*)d_in[13];
    float* out = (float*)d_out;

    // Workspace layout (floats), total 19.25 M floats = 77.0 MB.
    // NOTE (round-7 bug fix): every MTOT*DINNER bf16 array = 4,194,304 u16
    // = 2,097,152 floats — previously sized at half that, causing overlap
    // (and fp32 bits read as bf16 -> NaN).
    float* ws    = (float*)d_ws;
    float* hreg  = ws;                    // 2 M : hb bf16 (1M floats as u16) / hfinal fp32 (2M)
    float* xcbF  = hreg  + 2097152;       // 2 M : xc bf16
    float* szbF  = xcbF  + 2097152;       // 2 M : silu(z) bf16
    float* ubF   = szbF  + 2097152;       // 2 M : u bf16
    float* xdbl  = ubF   + 2097152;       // 256 K fp32 (B/C cols + dtsum scratch)
    float* dtbF  = xdbl  + 262144;        // 2 M : dt bf16
    float* ybF   = dtbF  + 2097152;       // 2 M : y bf16
    float* parts = ybF   + 2097152;       // 4 M : xpart (1M) | out partials (2x2M)
    float* wxzF  = parts + 4194304;       // 2 M : Wxz bf16, all layers
    float* woutF = wxzF  + 2097152;       // 1 M : Wout bf16, all layers

    u16* hb     = (u16*)hreg;
    float* hfinal = hreg;                 // alive scan1..scan3 only (hb dead then)
    u16* xcb  = (u16*)xcbF;
    u16* szb  = (u16*)szbF;
    u16* ub   = (u16*)ubF;
    u16* dtb  = (u16*)dtbF;
    u16* yb   = (u16*)ybF;
    float* xpart = parts;                 // dead after dtsum_kernel
    float* part0 = parts;                 // out-GEMM split-K partials (after scan3)
    float* part1 = parts + 2097152;
    u16* wxzb  = (u16*)wxzF;
    u16* woutb = (u16*)woutF;

    // Convert all layers' GEMM weights to bf16 once.
    wconv_kernel<<<(DEPTH_*2048*DMODEL/8)/256, 256, 0, stream>>>(W_xz, wxzb);
    wconv_kernel<<<(DEPTH_*DMODEL*DINNER/8)/256, 256, 0, stream>>>(W_out, woutb);

    in_proj_kernel<<<MTOT*DMODEL/256, 256, 0, stream>>>(x, in_w, in_b, hb);

    for (int layer = 0; layer < DEPTH_; ++layer) {
        const float* cw   = conv_w + (size_t)layer * DINNER * DCONV;
        const float* cb   = conv_b + (size_t)layer * DINNER;
        const float* Wxp  = W_xp   + (size_t)layer * 64 * DINNER;
        const float* Wdt  = W_dt   + (size_t)layer * DINNER * DTRANK;
        const float* bdt  = b_dt   + (size_t)layer * DINNER;
        const float* Alog = A_log  + (size_t)layer * DINNER * DSTATE;
        const float* Dp   = D_par  + (size_t)layer * DINNER;
        const u16* wxzL   = wxzb  + (size_t)layer * 2048 * DMODEL;
        const u16* woutL  = woutb + (size_t)layer * DMODEL * DINNER;

        // xz GEMM (K=512) with fused epilogue: bf16 xc + bf16 silu(z)
        gemm_bf16<128,1><<<dim3(2048/128, MTOT/128, 1), 256, 0, stream>>>(
            hb, DMODEL, wxzL, DMODEL, xcb, szb, 0, DMODEL, 0);
        // u = silu(conv(xc) + cb)
        conv_silu_kernel<<<MTOT*DINNER/2/256, 256, 0, stream>>>(xcb, cw, cb, ub);
        // xdbl partials (K-split x4)
        xp_kernel<<<dim3(4, MTOT/16), 256, 0, stream>>>(ub, Wxp, xpart);
        // fused partial-sum + dt GEMM + softplus
        dtsum_kernel<<<MTOT/8, 256, 0, stream>>>(xpart, Wdt, bdt, xdbl, dtb);
        // chunked selective scan
        scan1_kernel<<<B_*CHUNKS*(DINNER/256), 256, 0, stream>>>(ub, xdbl, dtb, Alog, hfinal, xdbl);
        scan2_kernel<<<(B_*DINNER*DSTATE)/256, 256, 0, stream>>>(hfinal, xdbl, Alog);
        scan3_kernel<<<B_*CHUNKS*(DINNER/256), 256, 0, stream>>>(szb, ub, xdbl, dtb, Alog, Dp, hfinal, yb);
        // h = y @ Wout^T (K=1024, split-K x2 -> fp32 partials -> bf16 combine)
        gemm_bf16<64,0><<<dim3(DMODEL/64, MTOT/128, 2), 256, 0, stream>>>(
            yb, DINNER, woutL, DINNER, part0, nullptr, DMODEL, DINNER/2,
            (size_t)MTOT * DMODEL);
        combine2_kernel<<<(MTOT*DMODEL/4)/256, 256, 0, stream>>>(part0, part1, hb);
    }

    ln_kernel<<<MTOT, 256, 0, stream>>>(hb, ln_g, ln_b, out);
}